// Round 13
// baseline (419.866 us; speedup 1.0000x reference)
//
#include <hip/hip_runtime.h>
#include <hip/hip_bf16.h>
#include <stdint.h>

using u16 = unsigned short;
using u32t = unsigned int;
typedef __bf16 bf16x8 __attribute__((ext_vector_type(8)));
typedef float f32x4 __attribute__((ext_vector_type(4)));
typedef float f32x16 __attribute__((ext_vector_type(16)));

#define SEQ_T 2048
#define DM 1024
#define NH 16
#define HD 64
#define NB 4

__device__ inline u16 f2bfu(float f) {
    __hip_bfloat16 h = __float2bfloat16(f);
    return __builtin_bit_cast(u16, h);
}

__device__ inline bf16x8 ld_frag(const u16* p) {
    return __builtin_bit_cast(bf16x8, *reinterpret_cast<const uint4*>(p));
}

__device__ inline void gload_lds16(const u16* g, u16* l) {
    __builtin_amdgcn_global_load_lds(
        (const __attribute__((address_space(1))) void*)g,
        (__attribute__((address_space(3))) void*)l, 16, 0, 0);
}

// ---------------- convert x (f32 -> bf16), 8 elems/thread ----------------
__global__ __launch_bounds__(256) void cvt_x_kernel(const float* __restrict__ x,
                                                    u16* __restrict__ o) {
    size_t i = (size_t)blockIdx.x * 256 + threadIdx.x;
    const float4* xv = reinterpret_cast<const float4*>(x);
    float4 a = xv[2 * i];
    float4 b = xv[2 * i + 1];
    u16 r[8] = {f2bfu(a.x), f2bfu(a.y), f2bfu(a.z), f2bfu(a.w),
                f2bfu(b.x), f2bfu(b.y), f2bfu(b.z), f2bfu(b.w)};
    *reinterpret_cast<uint4*>(o + i * 8) = *reinterpret_cast<const uint4*>(r);
}

// ---------------- transpose + convert W[K][N] f32 -> Wt[N][K] bf16 ----------------
__global__ __launch_bounds__(256) void trans_w(const float* __restrict__ W,
                                               u16* __restrict__ Wt,
                                               int K, int N) {
    __shared__ __align__(16) float tile[64][72];
    int k0 = blockIdx.y * 64, n0 = blockIdx.x * 64;
    int tid = threadIdx.x;
#pragma unroll
    for (int p = 0; p < 4; ++p) {
        int idx = p * 256 + tid;
        int r = idx >> 4, c = (idx & 15) * 4;
        float4 v = *reinterpret_cast<const float4*>(&W[(size_t)(k0 + r) * N + n0 + c]);
        *reinterpret_cast<float4*>(&tile[r][c]) = v;
    }
    __syncthreads();
#pragma unroll
    for (int p = 0; p < 4; ++p) {
        int idx = p * 256 + tid;
        int nr = idx >> 4, kg = (idx & 15) * 4;
        u16 u[4];
#pragma unroll
        for (int j = 0; j < 4; ++j) u[j] = f2bfu(tile[kg + j][nr]);
        *reinterpret_cast<uint2*>(&Wt[(size_t)(n0 + nr) * K + k0 + kg]) =
            *reinterpret_cast<const uint2*>(u);
    }
}

// ---------------- GEMM: C[M,N] = A[M,K] @ Bt[N,K]^T + bias ----------------
// 1D grid; XCD-aware decode: xcd = bid&7 owns NX/8 contiguous n-panels (B L2 reuse).
template <int F32OUT, int NX>
__global__ __launch_bounds__(256) void gemm_bt(const u16* __restrict__ A,
                                               const u16* __restrict__ Bt,
                                               const float* __restrict__ bias,
                                               float* __restrict__ Cf,
                                               u16* __restrict__ Cb,
                                               int M, int N, int K) {
    __shared__ __align__(16) u16 As[128 * 32];
    __shared__ __align__(16) u16 Bs[128 * 32];
    const int tid = threadIdx.x;
    const int wid = tid >> 6, lane = tid & 63;
    const int lhi = lane >> 4, llo = lane & 15;
    const int xcd = blockIdx.x & 7;
    const int bi = blockIdx.x >> 3;
    const int npx = NX >> 3;
    const int n0 = (xcd * npx + (bi % npx)) * 128;
    const int m0 = (bi / npx) * 128;
    const int wr = wid >> 1, wc = wid & 1;

    f32x4 acc[4][4];
#pragma unroll
    for (int i = 0; i < 4; ++i)
#pragma unroll
        for (int j = 0; j < 4; ++j) acc[i][j] = (f32x4){0.f, 0.f, 0.f, 0.f};

    for (int k0 = 0; k0 < K; k0 += 32) {
        __syncthreads();
#pragma unroll
        for (int p = 0; p < 2; ++p) {
            int idx = p * 256 + tid;
            int row = idx >> 2, kc = (idx & 3) * 8;
            gload_lds16(A + (size_t)(m0 + row) * K + k0 + kc,
                        As + (size_t)(p * 256 + wid * 64) * 8);
            gload_lds16(Bt + (size_t)(n0 + row) * K + k0 + kc,
                        Bs + (size_t)(p * 256 + wid * 64) * 8);
        }
        __syncthreads();
        bf16x8 af[4], bfr[4];
#pragma unroll
        for (int mt = 0; mt < 4; ++mt)
            af[mt] = ld_frag(&As[(wr * 64 + mt * 16 + llo) * 32 + lhi * 8]);
#pragma unroll
        for (int nt = 0; nt < 4; ++nt)
            bfr[nt] = ld_frag(&Bs[(wc * 64 + nt * 16 + llo) * 32 + lhi * 8]);
#pragma unroll
        for (int mt = 0; mt < 4; ++mt)
#pragma unroll
            for (int nt = 0; nt < 4; ++nt)
                acc[mt][nt] = __builtin_amdgcn_mfma_f32_16x16x32_bf16(
                    af[mt], bfr[nt], acc[mt][nt], 0, 0, 0);
    }

    const int row_base = m0 + wr * 64;
    const int col_base = n0 + wc * 64;
#pragma unroll
    for (int nt = 0; nt < 4; ++nt) {
        int col = col_base + nt * 16 + llo;
        float bv = bias[col];
#pragma unroll
        for (int mt = 0; mt < 4; ++mt) {
#pragma unroll
            for (int r = 0; r < 4; ++r) {
                int row = row_base + mt * 16 + lhi * 4 + r;
                float v = acc[mt][nt][r] + bv;
                if (F32OUT)
                    Cf[(size_t)row * N + col] = v;
                else
                    Cb[(size_t)row * N + col] = f2bfu(v);
            }
        }
    }
}

// ---------------- causal flash attention, 8-wave blocks (256 q rows) ----------------
// Block: 512 thr (8 waves), wave owns 32 q rows -> block = 256 q rows.
// Grid: 512 = 8 q-chunks x 64 (b,h) = exactly 2 blocks/CU, all resident.
// K/V staged once per block for 2x the q rows of the old 4-wave version:
// halves HBM re-fetch and barrier-drain events per unit work.
__global__ __launch_bounds__(512, 4) void attn_kernel(const u16* __restrict__ qkv,
                                                      u16* __restrict__ o) {
    __shared__ __align__(16) u16 smem[17920];  // K:2x4160 @0, Vt:2x4608 @8320; epi 8x2240
    const int bid = blockIdx.x;
    const int qcmap[8] = {7, 6, 5, 4, 0, 1, 2, 3};  // classes (g,g+4) sum to 7
    const int qc = qcmap[bid >> 6];
    const int bh = bid & 63;
    const int b = bh >> 4, h = bh & 15;
    const int tid = threadIdx.x;
    const int wid = tid >> 6, lane = tid & 63;
    const int l31 = lane & 31, lh = lane >> 5;
    const u16* base = qkv + (size_t)b * SEQ_T * (3 * DM);
    const int qrow0 = qc * 256 + wid * 32;
    const int q_abs = qrow0 + l31;
    const int nkv = 4 * qc + 4;

    bf16x8 qf[4];
    {
        const u16* qp = base + (size_t)q_abs * (3 * DM) + h * HD + lh * 8;
#pragma unroll
        for (int km = 0; km < 4; ++km) qf[km] = ld_frag(qp + km * 16);
    }

    f32x16 oac0, oac1;
#pragma unroll
    for (int r = 0; r < 16; ++r) { oac0[r] = 0.f; oac1[r] = 0.f; }
    float m_run = -1e30f, l_run = 0.f;

    uint4 va;
    const int vpr = tid >> 3, vm = tid & 7;  // vpr = V row (0..63), vm = d-slice

    auto stageK = [&](int kb, int bi2) {
        // 512 threads cover 64 rows x 64 cols exactly once
        int kv = wid * 8 + (lane >> 3);
        int cl = lane & 7;
        const u16* src = base + (size_t)(kb * 64 + kv) * (3 * DM) + DM + h * HD +
                         ((cl ^ (kv & 7)) * 8);
        gload_lds16(src, smem + bi2 * 4160 + wid * 520);
    };
    auto loadV = [&](int kb) {
        const u16* vp =
            base + (size_t)(kb * 64 + vpr) * (3 * DM) + 2 * DM + h * HD + vm * 8;
        va = *reinterpret_cast<const uint4*>(vp);
    };
    auto writeV = [&](int bi2) {  // Vt[d][kv]: col c at 8*((c>>3)^sw(d)) + (c&7)
        u16 ua[8];
        *reinterpret_cast<uint4*>(ua) = va;
        const int sw = (2 * vm) & 7;  // sw(d) for d = vm*8+j (all j: d>>3 == vm)
        const int col = ((vpr >> 3) ^ sw) * 8 + (vpr & 7);
        u16* vt = smem + 8320 + bi2 * 4608;
#pragma unroll
        for (int j = 0; j < 8; ++j) vt[(vm * 8 + j) * 72 + col] = ua[j];
    };

    loadV(0);
    stageK(0, 0);
    writeV(0);
    __syncthreads();

    const int vsw = (2 * (l31 >> 3)) & 7;
    const int qmax = qrow0 + 31;
    const float SC2 = 0.18033688f;  // (1/sqrt(64)) * log2(e); softmax in base-2
    const int krow0 = (l31 >> 3) * 520 + (l31 & 7) * 64;
    const int krow1 = (4 + (l31 >> 3)) * 520 + (l31 & 7) * 64;

    for (int kb = 0; kb < nkv; ++kb) {
        const int cur = kb & 1;
        const bool pre = (kb + 1 < nkv);
        if (pre) { loadV(kb + 1); stageK(kb + 1, cur ^ 1); }

        if (kb * 64 <= qmax) {
            // ---- S^T = K · Q^T ----
            f32x16 s0, s1;
#pragma unroll
            for (int r = 0; r < 16; ++r) { s0[r] = 0.f; s1[r] = 0.f; }
            const u16* kbase = smem + cur * 4160;
#pragma unroll
            for (int km = 0; km < 4; ++km) {
                bf16x8 kf = ld_frag(kbase + krow0 + (((km * 2 + lh) ^ (l31 & 7)) * 8));
                s0 = __builtin_amdgcn_mfma_f32_32x32x16_bf16(kf, qf[km], s0, 0, 0, 0);
            }
#pragma unroll
            for (int km = 0; km < 4; ++km) {
                bf16x8 kf = ld_frag(kbase + krow1 + (((km * 2 + lh) ^ (l31 & 7)) * 8));
                s1 = __builtin_amdgcn_mfma_f32_32x32x16_bf16(kf, qf[km], s1, 0, 0, 0);
            }

            // ---- scale + causal mask ----
            if (kb * 64 + 63 > qrow0) {
#pragma unroll
                for (int r = 0; r < 16; ++r) {
                    int ka = kb * 64 + (r & 3) + 8 * (r >> 2) + 4 * lh;
                    s0[r] = (ka > q_abs) ? -1e30f : s0[r] * SC2;
                    s1[r] = (ka + 32 > q_abs) ? -1e30f : s1[r] * SC2;
                }
            } else {
#pragma unroll
                for (int r = 0; r < 16; ++r) { s0[r] *= SC2; s1[r] *= SC2; }
            }

            // ---- online softmax, tree reductions, defer-max ----
            float t16[16];
#pragma unroll
            for (int r = 0; r < 16; ++r) t16[r] = fmaxf(s0[r], s1[r]);
#pragma unroll
            for (int r = 0; r < 8; ++r) t16[r] = fmaxf(t16[r], t16[r + 8]);
#pragma unroll
            for (int r = 0; r < 4; ++r) t16[r] = fmaxf(t16[r], t16[r + 4]);
            float pm = fmaxf(fmaxf(t16[0], t16[1]), fmaxf(t16[2], t16[3]));
            pm = fmaxf(pm, __shfl_xor(pm, 32));
            if (!__all(pm - m_run <= 8.f)) {
                const float mnew = fmaxf(m_run, pm);
                const float sc = exp2f(m_run - mnew);
                m_run = mnew;
                l_run *= sc;
#pragma unroll
                for (int r = 0; r < 16; ++r) { oac0[r] *= sc; oac1[r] *= sc; }
            }
            float a16[16];
#pragma unroll
            for (int r = 0; r < 16; ++r) { s0[r] = exp2f(s0[r] - m_run); }
#pragma unroll
            for (int r = 0; r < 16; ++r) { s1[r] = exp2f(s1[r] - m_run); }
#pragma unroll
            for (int r = 0; r < 16; ++r) a16[r] = s0[r] + s1[r];
#pragma unroll
            for (int r = 0; r < 8; ++r) a16[r] += a16[r + 8];
#pragma unroll
            for (int r = 0; r < 4; ++r) a16[r] += a16[r + 4];
            float sum = (a16[0] + a16[1]) + (a16[2] + a16[3]);
            sum += __shfl_xor(sum, 32);
            l_run += sum;

            // ---- P -> bf16 B-fragments: cvt_pk + permlane32_swap ----
            u32t pk0[8], pk1[8];
#pragma unroll
            for (int w = 0; w < 8; ++w) {
                float a0 = s0[2 * w], b0 = s0[2 * w + 1];
                float a1 = s1[2 * w], b1 = s1[2 * w + 1];
                asm("v_cvt_pk_bf16_f32 %0, %1, %2" : "=v"(pk0[w]) : "v"(a0), "v"(b0));
                asm("v_cvt_pk_bf16_f32 %0, %1, %2" : "=v"(pk1[w]) : "v"(a1), "v"(b1));
            }
            asm("v_permlane32_swap_b32 %0, %1" : "+v"(pk0[0]), "+v"(pk0[2]));
            asm("v_permlane32_swap_b32 %0, %1" : "+v"(pk0[1]), "+v"(pk0[3]));
            asm("v_permlane32_swap_b32 %0, %1" : "+v"(pk0[4]), "+v"(pk0[6]));
            asm("v_permlane32_swap_b32 %0, %1" : "+v"(pk0[5]), "+v"(pk0[7]));
            asm("v_permlane32_swap_b32 %0, %1" : "+v"(pk1[0]), "+v"(pk1[2]));
            asm("v_permlane32_swap_b32 %0, %1" : "+v"(pk1[1]), "+v"(pk1[3]));
            asm("v_permlane32_swap_b32 %0, %1" : "+v"(pk1[4]), "+v"(pk1[6]));
            asm("v_permlane32_swap_b32 %0, %1" : "+v"(pk1[5]), "+v"(pk1[7]));
            bf16x8 pf[4];
            {
                uint4 t0 = {pk0[0], pk0[1], pk0[2], pk0[3]};
                uint4 t1 = {pk0[4], pk0[5], pk0[6], pk0[7]};
                uint4 t2 = {pk1[0], pk1[1], pk1[2], pk1[3]};
                uint4 t3 = {pk1[4], pk1[5], pk1[6], pk1[7]};
                pf[0] = __builtin_bit_cast(bf16x8, t0);
                pf[1] = __builtin_bit_cast(bf16x8, t1);
                pf[2] = __builtin_bit_cast(bf16x8, t2);
                pf[3] = __builtin_bit_cast(bf16x8, t3);
            }

            // ---- O^T += V^T · P^T ----
            const u16* vbase = smem + 8320 + cur * 4608;
#pragma unroll
            for (int km = 0; km < 4; ++km) {
                bf16x8 vf = ld_frag(vbase + l31 * 72 + (((km * 2 + lh) ^ vsw) * 8));
                oac0 = __builtin_amdgcn_mfma_f32_32x32x16_bf16(vf, pf[km], oac0, 0, 0, 0);
            }
#pragma unroll
            for (int km = 0; km < 4; ++km) {
                bf16x8 vf = ld_frag(vbase + (32 + l31) * 72 + (((km * 2 + lh) ^ vsw) * 8));
                oac1 = __builtin_amdgcn_mfma_f32_32x32x16_bf16(vf, pf[km], oac1, 0, 0, 0);
            }
        }

        if (pre) writeV(cur ^ 1);
        __syncthreads();
    }

    // ---- epilogue: normalize, transpose O^T->O via LDS, coalesced store ----
    const float inv = 1.f / l_run;
    u16* osh = smem + wid * 2240;  // per-wave [32 q][70 u16]; 8 waves = 17920 u16
#pragma unroll
    for (int r = 0; r < 16; ++r) {
        int dl = (r & 3) + 8 * (r >> 2) + 4 * lh;
        osh[l31 * 70 + dl] = f2bfu(oac0[r] * inv);
        osh[l31 * 70 + 32 + dl] = f2bfu(oac1[r] * inv);
    }
    __syncthreads();
    {
        const u16* rs = osh + l31 * 70 + lh * 32;
        u16* op = o + (size_t)(b * SEQ_T + qrow0 + l31) * DM + h * HD + lh * 32;
        u32t w[16];
#pragma unroll
        for (int i = 0; i < 16; ++i) w[i] = *reinterpret_cast<const u32t*>(rs + i * 2);
#pragma unroll
        for (int i = 0; i < 4; ++i) {
            uint4 t = {w[4 * i], w[4 * i + 1], w[4 * i + 2], w[4 * i + 3]};
            *reinterpret_cast<uint4*>(op + 8 * i) = t;
        }
    }
}

extern "C" void kernel_launch(void* const* d_in, const int* in_sizes, int n_in,
                              void* d_out, int out_size, void* d_ws, size_t ws_size,
                              hipStream_t stream) {
    const float* x = (const float*)d_in[0];
    const float* Wqkv = (const float*)d_in[1];
    const float* bqkv = (const float*)d_in[2];
    const float* Wproj = (const float*)d_in[3];
    const float* bproj = (const float*)d_in[4];
    float* out = (float*)d_out;
    char* ws = (char*)d_ws;

    u16* xb   = (u16*)(ws);                         // 16,777,216 B
    u16* wtq  = (u16*)(ws + 16777216);              //  6,291,456 B
    u16* wtp  = (u16*)(ws + 23068672);              //  2,097,152 B
    u16* qkvb = (u16*)(ws + 25165824);              // 50,331,648 B
    u16* ob   = (u16*)(ws + 75497472);              // 16,777,216 B

    cvt_x_kernel<<<4096, 256, 0, stream>>>(x, xb);
    trans_w<<<dim3(3072 / 64, 1024 / 64), 256, 0, stream>>>(Wqkv, wtq, 1024, 3072);
    trans_w<<<dim3(1024 / 64, 1024 / 64), 256, 0, stream>>>(Wproj, wtp, 1024, 1024);

    gemm_bt<0, 24><<<1536, 256, 0, stream>>>(
        xb, wtq, bqkv, nullptr, qkvb, 8192, 3072, 1024);

    attn_kernel<<<512, 512, 0, stream>>>(qkvb, ob);

    gemm_bt<1, 8><<<512, 256, 0, stream>>>(
        ob, wtp, bproj, out, nullptr, 8192, 1024, 1024);
}

// Round 14
// 224.951 us; speedup vs baseline: 1.8665x; 1.8665x over previous
//
#include <hip/hip_runtime.h>
#include <hip/hip_bf16.h>
#include <stdint.h>

using u16 = unsigned short;
using u32t = unsigned int;
typedef __bf16 bf16x8 __attribute__((ext_vector_type(8)));
typedef float f32x4 __attribute__((ext_vector_type(4)));
typedef float f32x16 __attribute__((ext_vector_type(16)));

#define SEQ_T 2048
#define DM 1024
#define NH 16
#define HD 64
#define NB 4

__device__ inline u16 f2bfu(float f) {
    __hip_bfloat16 h = __float2bfloat16(f);
    return __builtin_bit_cast(u16, h);
}

__device__ inline bf16x8 ld_frag(const u16* p) {
    return __builtin_bit_cast(bf16x8, *reinterpret_cast<const uint4*>(p));
}

__device__ inline void gload_lds16(const u16* g, u16* l) {
    __builtin_amdgcn_global_load_lds(
        (const __attribute__((address_space(1))) void*)g,
        (__attribute__((address_space(3))) void*)l, 16, 0, 0);
}

// ---------------- convert x (f32 -> bf16), 8 elems/thread ----------------
__global__ __launch_bounds__(256) void cvt_x_kernel(const float* __restrict__ x,
                                                    u16* __restrict__ o) {
    size_t i = (size_t)blockIdx.x * 256 + threadIdx.x;
    const float4* xv = reinterpret_cast<const float4*>(x);
    float4 a = xv[2 * i];
    float4 b = xv[2 * i + 1];
    u16 r[8] = {f2bfu(a.x), f2bfu(a.y), f2bfu(a.z), f2bfu(a.w),
                f2bfu(b.x), f2bfu(b.y), f2bfu(b.z), f2bfu(b.w)};
    *reinterpret_cast<uint4*>(o + i * 8) = *reinterpret_cast<const uint4*>(r);
}

// ---------------- transpose + convert W[K][N] f32 -> Wt[N][K] bf16 ----------------
__global__ __launch_bounds__(256) void trans_w(const float* __restrict__ W,
                                               u16* __restrict__ Wt,
                                               int K, int N) {
    __shared__ __align__(16) float tile[64][72];
    int k0 = blockIdx.y * 64, n0 = blockIdx.x * 64;
    int tid = threadIdx.x;
#pragma unroll
    for (int p = 0; p < 4; ++p) {
        int idx = p * 256 + tid;
        int r = idx >> 4, c = (idx & 15) * 4;
        float4 v = *reinterpret_cast<const float4*>(&W[(size_t)(k0 + r) * N + n0 + c]);
        *reinterpret_cast<float4*>(&tile[r][c]) = v;
    }
    __syncthreads();
#pragma unroll
    for (int p = 0; p < 4; ++p) {
        int idx = p * 256 + tid;
        int nr = idx >> 4, kg = (idx & 15) * 4;
        u16 u[4];
#pragma unroll
        for (int j = 0; j < 4; ++j) u[j] = f2bfu(tile[kg + j][nr]);
        *reinterpret_cast<uint2*>(&Wt[(size_t)(n0 + nr) * K + k0 + kg]) =
            *reinterpret_cast<const uint2*>(u);
    }
}

// ---------------- GEMM: C[M,N] = A[M,K] @ Bt[N,K]^T + bias ----------------
// 1D grid; XCD-aware decode: xcd = bid&7 owns NX/8 contiguous n-panels (B L2 reuse).
template <int F32OUT, int NX>
__global__ __launch_bounds__(256) void gemm_bt(const u16* __restrict__ A,
                                               const u16* __restrict__ Bt,
                                               const float* __restrict__ bias,
                                               float* __restrict__ Cf,
                                               u16* __restrict__ Cb,
                                               int M, int N, int K) {
    __shared__ __align__(16) u16 As[128 * 32];
    __shared__ __align__(16) u16 Bs[128 * 32];
    const int tid = threadIdx.x;
    const int wid = tid >> 6, lane = tid & 63;
    const int lhi = lane >> 4, llo = lane & 15;
    const int xcd = blockIdx.x & 7;
    const int bi = blockIdx.x >> 3;
    const int npx = NX >> 3;
    const int n0 = (xcd * npx + (bi % npx)) * 128;
    const int m0 = (bi / npx) * 128;
    const int wr = wid >> 1, wc = wid & 1;

    f32x4 acc[4][4];
#pragma unroll
    for (int i = 0; i < 4; ++i)
#pragma unroll
        for (int j = 0; j < 4; ++j) acc[i][j] = (f32x4){0.f, 0.f, 0.f, 0.f};

    for (int k0 = 0; k0 < K; k0 += 32) {
        __syncthreads();
#pragma unroll
        for (int p = 0; p < 2; ++p) {
            int idx = p * 256 + tid;
            int row = idx >> 2, kc = (idx & 3) * 8;
            gload_lds16(A + (size_t)(m0 + row) * K + k0 + kc,
                        As + (size_t)(p * 256 + wid * 64) * 8);
            gload_lds16(Bt + (size_t)(n0 + row) * K + k0 + kc,
                        Bs + (size_t)(p * 256 + wid * 64) * 8);
        }
        __syncthreads();
        bf16x8 af[4], bfr[4];
#pragma unroll
        for (int mt = 0; mt < 4; ++mt)
            af[mt] = ld_frag(&As[(wr * 64 + mt * 16 + llo) * 32 + lhi * 8]);
#pragma unroll
        for (int nt = 0; nt < 4; ++nt)
            bfr[nt] = ld_frag(&Bs[(wc * 64 + nt * 16 + llo) * 32 + lhi * 8]);
#pragma unroll
        for (int mt = 0; mt < 4; ++mt)
#pragma unroll
            for (int nt = 0; nt < 4; ++nt)
                acc[mt][nt] = __builtin_amdgcn_mfma_f32_16x16x32_bf16(
                    af[mt], bfr[nt], acc[mt][nt], 0, 0, 0);
    }

    const int row_base = m0 + wr * 64;
    const int col_base = n0 + wc * 64;
#pragma unroll
    for (int nt = 0; nt < 4; ++nt) {
        int col = col_base + nt * 16 + llo;
        float bv = bias[col];
#pragma unroll
        for (int mt = 0; mt < 4; ++mt) {
#pragma unroll
            for (int r = 0; r < 4; ++r) {
                int row = row_base + mt * 16 + lhi * 4 + r;
                float v = acc[mt][nt][r] + bv;
                if (F32OUT)
                    Cf[(size_t)row * N + col] = v;
                else
                    Cb[(size_t)row * N + col] = f2bfu(v);
            }
        }
    }
}

// ---------------- causal flash attention, 8-wave blocks (256 q rows) ----------------
// Block: 512 thr (8 waves), wave owns 32 q rows -> block = 256 q rows.
// Grid: 512 = 8 q-chunks x 64 (b,h) = exactly 2 blocks/CU, all resident.
// launch_bounds (512,2): VGPR cap 256 -> natural ~84-110 alloc, 4 waves/SIMD,
// no spills (round-13's (512,4) forced a 64-VGPR cap -> scratch thrash).
__global__ __launch_bounds__(512, 2) void attn_kernel(const u16* __restrict__ qkv,
                                                      u16* __restrict__ o) {
    __shared__ __align__(16) u16 smem[17920];  // K:2x4160 @0, Vt:2x4608 @8320; epi 8x2240
    const int bid = blockIdx.x;
    const int qcmap[8] = {7, 6, 5, 4, 0, 1, 2, 3};  // classes (g,g+4) sum to 7
    const int qc = qcmap[bid >> 6];
    const int bh = bid & 63;
    const int b = bh >> 4, h = bh & 15;
    const int tid = threadIdx.x;
    const int wid = tid >> 6, lane = tid & 63;
    const int l31 = lane & 31, lh = lane >> 5;
    const u16* base = qkv + (size_t)b * SEQ_T * (3 * DM);
    const int qrow0 = qc * 256 + wid * 32;
    const int q_abs = qrow0 + l31;
    const int nkv = 4 * qc + 4;

    bf16x8 qf[4];
    {
        const u16* qp = base + (size_t)q_abs * (3 * DM) + h * HD + lh * 8;
#pragma unroll
        for (int km = 0; km < 4; ++km) qf[km] = ld_frag(qp + km * 16);
    }

    f32x16 oac0, oac1;
#pragma unroll
    for (int r = 0; r < 16; ++r) { oac0[r] = 0.f; oac1[r] = 0.f; }
    float m_run = -1e30f, l_run = 0.f;

    uint4 va;
    const int vpr = tid >> 3, vm = tid & 7;  // vpr = V row (0..63), vm = d-slice

    auto stageK = [&](int kb, int bi2) {
        // 512 threads cover 64 rows x 64 cols exactly once
        int kv = wid * 8 + (lane >> 3);
        int cl = lane & 7;
        const u16* src = base + (size_t)(kb * 64 + kv) * (3 * DM) + DM + h * HD +
                         ((cl ^ (kv & 7)) * 8);
        gload_lds16(src, smem + bi2 * 4160 + wid * 520);
    };
    auto loadV = [&](int kb) {
        const u16* vp =
            base + (size_t)(kb * 64 + vpr) * (3 * DM) + 2 * DM + h * HD + vm * 8;
        va = *reinterpret_cast<const uint4*>(vp);
    };
    auto writeV = [&](int bi2) {  // Vt[d][kv]: col c at 8*((c>>3)^sw(d)) + (c&7)
        u16 ua[8];
        *reinterpret_cast<uint4*>(ua) = va;
        const int sw = (2 * vm) & 7;  // sw(d) for d = vm*8+j (all j: d>>3 == vm)
        const int col = ((vpr >> 3) ^ sw) * 8 + (vpr & 7);
        u16* vt = smem + 8320 + bi2 * 4608;
#pragma unroll
        for (int j = 0; j < 8; ++j) vt[(vm * 8 + j) * 72 + col] = ua[j];
    };

    loadV(0);
    stageK(0, 0);
    writeV(0);
    __syncthreads();

    const int vsw = (2 * (l31 >> 3)) & 7;
    const int qmax = qrow0 + 31;
    const float SC2 = 0.18033688f;  // (1/sqrt(64)) * log2(e); softmax in base-2
    const int krow0 = (l31 >> 3) * 520 + (l31 & 7) * 64;
    const int krow1 = (4 + (l31 >> 3)) * 520 + (l31 & 7) * 64;

    for (int kb = 0; kb < nkv; ++kb) {
        const int cur = kb & 1;
        const bool pre = (kb + 1 < nkv);
        if (pre) { loadV(kb + 1); stageK(kb + 1, cur ^ 1); }

        if (kb * 64 <= qmax) {
            // ---- S^T = K · Q^T ----
            f32x16 s0, s1;
#pragma unroll
            for (int r = 0; r < 16; ++r) { s0[r] = 0.f; s1[r] = 0.f; }
            const u16* kbase = smem + cur * 4160;
#pragma unroll
            for (int km = 0; km < 4; ++km) {
                bf16x8 kf = ld_frag(kbase + krow0 + (((km * 2 + lh) ^ (l31 & 7)) * 8));
                s0 = __builtin_amdgcn_mfma_f32_32x32x16_bf16(kf, qf[km], s0, 0, 0, 0);
            }
#pragma unroll
            for (int km = 0; km < 4; ++km) {
                bf16x8 kf = ld_frag(kbase + krow1 + (((km * 2 + lh) ^ (l31 & 7)) * 8));
                s1 = __builtin_amdgcn_mfma_f32_32x32x16_bf16(kf, qf[km], s1, 0, 0, 0);
            }

            // ---- scale + causal mask ----
            if (kb * 64 + 63 > qrow0) {
#pragma unroll
                for (int r = 0; r < 16; ++r) {
                    int ka = kb * 64 + (r & 3) + 8 * (r >> 2) + 4 * lh;
                    s0[r] = (ka > q_abs) ? -1e30f : s0[r] * SC2;
                    s1[r] = (ka + 32 > q_abs) ? -1e30f : s1[r] * SC2;
                }
            } else {
#pragma unroll
                for (int r = 0; r < 16; ++r) { s0[r] *= SC2; s1[r] *= SC2; }
            }

            // ---- online softmax, tree reductions, defer-max ----
            float t16[16];
#pragma unroll
            for (int r = 0; r < 16; ++r) t16[r] = fmaxf(s0[r], s1[r]);
#pragma unroll
            for (int r = 0; r < 8; ++r) t16[r] = fmaxf(t16[r], t16[r + 8]);
#pragma unroll
            for (int r = 0; r < 4; ++r) t16[r] = fmaxf(t16[r], t16[r + 4]);
            float pm = fmaxf(fmaxf(t16[0], t16[1]), fmaxf(t16[2], t16[3]));
            pm = fmaxf(pm, __shfl_xor(pm, 32));
            if (!__all(pm - m_run <= 8.f)) {
                const float mnew = fmaxf(m_run, pm);
                const float sc = exp2f(m_run - mnew);
                m_run = mnew;
                l_run *= sc;
#pragma unroll
                for (int r = 0; r < 16; ++r) { oac0[r] *= sc; oac1[r] *= sc; }
            }
            float a16[16];
#pragma unroll
            for (int r = 0; r < 16; ++r) { s0[r] = exp2f(s0[r] - m_run); }
#pragma unroll
            for (int r = 0; r < 16; ++r) { s1[r] = exp2f(s1[r] - m_run); }
#pragma unroll
            for (int r = 0; r < 16; ++r) a16[r] = s0[r] + s1[r];
#pragma unroll
            for (int r = 0; r < 8; ++r) a16[r] += a16[r + 8];
#pragma unroll
            for (int r = 0; r < 4; ++r) a16[r] += a16[r + 4];
            float sum = (a16[0] + a16[1]) + (a16[2] + a16[3]);
            sum += __shfl_xor(sum, 32);
            l_run += sum;

            // ---- P -> bf16 B-fragments: cvt_pk + permlane32_swap ----
            u32t pk0[8], pk1[8];
#pragma unroll
            for (int w = 0; w < 8; ++w) {
                float a0 = s0[2 * w], b0 = s0[2 * w + 1];
                float a1 = s1[2 * w], b1 = s1[2 * w + 1];
                asm("v_cvt_pk_bf16_f32 %0, %1, %2" : "=v"(pk0[w]) : "v"(a0), "v"(b0));
                asm("v_cvt_pk_bf16_f32 %0, %1, %2" : "=v"(pk1[w]) : "v"(a1), "v"(b1));
            }
            asm("v_permlane32_swap_b32 %0, %1" : "+v"(pk0[0]), "+v"(pk0[2]));
            asm("v_permlane32_swap_b32 %0, %1" : "+v"(pk0[1]), "+v"(pk0[3]));
            asm("v_permlane32_swap_b32 %0, %1" : "+v"(pk0[4]), "+v"(pk0[6]));
            asm("v_permlane32_swap_b32 %0, %1" : "+v"(pk0[5]), "+v"(pk0[7]));
            asm("v_permlane32_swap_b32 %0, %1" : "+v"(pk1[0]), "+v"(pk1[2]));
            asm("v_permlane32_swap_b32 %0, %1" : "+v"(pk1[1]), "+v"(pk1[3]));
            asm("v_permlane32_swap_b32 %0, %1" : "+v"(pk1[4]), "+v"(pk1[6]));
            asm("v_permlane32_swap_b32 %0, %1" : "+v"(pk1[5]), "+v"(pk1[7]));
            bf16x8 pf[4];
            {
                uint4 t0 = {pk0[0], pk0[1], pk0[2], pk0[3]};
                uint4 t1 = {pk0[4], pk0[5], pk0[6], pk0[7]};
                uint4 t2 = {pk1[0], pk1[1], pk1[2], pk1[3]};
                uint4 t3 = {pk1[4], pk1[5], pk1[6], pk1[7]};
                pf[0] = __builtin_bit_cast(bf16x8, t0);
                pf[1] = __builtin_bit_cast(bf16x8, t1);
                pf[2] = __builtin_bit_cast(bf16x8, t2);
                pf[3] = __builtin_bit_cast(bf16x8, t3);
            }

            // ---- O^T += V^T · P^T ----
            const u16* vbase = smem + 8320 + cur * 4608;
#pragma unroll
            for (int km = 0; km < 4; ++km) {
                bf16x8 vf = ld_frag(vbase + l31 * 72 + (((km * 2 + lh) ^ vsw) * 8));
                oac0 = __builtin_amdgcn_mfma_f32_32x32x16_bf16(vf, pf[km], oac0, 0, 0, 0);
            }
#pragma unroll
            for (int km = 0; km < 4; ++km) {
                bf16x8 vf = ld_frag(vbase + (32 + l31) * 72 + (((km * 2 + lh) ^ vsw) * 8));
                oac1 = __builtin_amdgcn_mfma_f32_32x32x16_bf16(vf, pf[km], oac1, 0, 0, 0);
            }
        }

        if (pre) writeV(cur ^ 1);
        __syncthreads();
    }

    // ---- epilogue: normalize, transpose O^T->O via LDS, coalesced store ----
    const float inv = 1.f / l_run;
    u16* osh = smem + wid * 2240;  // per-wave [32 q][70 u16]; 8 waves = 17920 u16
#pragma unroll
    for (int r = 0; r < 16; ++r) {
        int dl = (r & 3) + 8 * (r >> 2) + 4 * lh;
        osh[l31 * 70 + dl] = f2bfu(oac0[r] * inv);
        osh[l31 * 70 + 32 + dl] = f2bfu(oac1[r] * inv);
    }
    __syncthreads();
    {
        const u16* rs = osh + l31 * 70 + lh * 32;
        u16* op = o + (size_t)(b * SEQ_T + qrow0 + l31) * DM + h * HD + lh * 32;
        u32t w[16];
#pragma unroll
        for (int i = 0; i < 16; ++i) w[i] = *reinterpret_cast<const u32t*>(rs + i * 2);
#pragma unroll
        for (int i = 0; i < 4; ++i) {
            uint4 t = {w[4 * i], w[4 * i + 1], w[4 * i + 2], w[4 * i + 3]};
            *reinterpret_cast<uint4*>(op + 8 * i) = t;
        }
    }
}

extern "C" void kernel_launch(void* const* d_in, const int* in_sizes, int n_in,
                              void* d_out, int out_size, void* d_ws, size_t ws_size,
                              hipStream_t stream) {
    const float* x = (const float*)d_in[0];
    const float* Wqkv = (const float*)d_in[1];
    const float* bqkv = (const float*)d_in[2];
    const float* Wproj = (const float*)d_in[3];
    const float* bproj = (const float*)d_in[4];
    float* out = (float*)d_out;
    char* ws = (char*)d_ws;

    u16* xb   = (u16*)(ws);                         // 16,777,216 B
    u16* wtq  = (u16*)(ws + 16777216);              //  6,291,456 B
    u16* wtp  = (u16*)(ws + 23068672);              //  2,097,152 B
    u16* qkvb = (u16*)(ws + 25165824);              // 50,331,648 B
    u16* ob   = (u16*)(ws + 75497472);              // 16,777,216 B

    cvt_x_kernel<<<4096, 256, 0, stream>>>(x, xb);
    trans_w<<<dim3(3072 / 64, 1024 / 64), 256, 0, stream>>>(Wqkv, wtq, 1024, 3072);
    trans_w<<<dim3(1024 / 64, 1024 / 64), 256, 0, stream>>>(Wproj, wtp, 1024, 1024);

    gemm_bt<0, 24><<<1536, 256, 0, stream>>>(
        xb, wtq, bqkv, nullptr, qkvb, 8192, 3072, 1024);

    attn_kernel<<<512, 512, 0, stream>>>(qkvb, ob);

    gemm_bt<1, 8><<<512, 256, 0, stream>>>(
        ob, wtp, bproj, out, nullptr, 8192, 1024, 1024);
}

// Round 15
// 216.080 us; speedup vs baseline: 1.9431x; 1.0411x over previous
//
#include <hip/hip_runtime.h>
#include <hip/hip_bf16.h>
#include <stdint.h>

using u16 = unsigned short;
using u32t = unsigned int;
typedef __bf16 bf16x8 __attribute__((ext_vector_type(8)));
typedef float f32x4 __attribute__((ext_vector_type(4)));
typedef float f32x16 __attribute__((ext_vector_type(16)));

#define SEQ_T 2048
#define DM 1024
#define NH 16
#define HD 64
#define NB 4

__device__ inline u16 f2bfu(float f) {
    __hip_bfloat16 h = __float2bfloat16(f);
    return __builtin_bit_cast(u16, h);
}

__device__ inline bf16x8 ld_frag(const u16* p) {
    return __builtin_bit_cast(bf16x8, *reinterpret_cast<const uint4*>(p));
}

__device__ inline void gload_lds16(const u16* g, u16* l) {
    __builtin_amdgcn_global_load_lds(
        (const __attribute__((address_space(1))) void*)g,
        (__attribute__((address_space(3))) void*)l, 16, 0, 0);
}

// ---------------- convert x (f32 -> bf16), 8 elems/thread ----------------
__global__ __launch_bounds__(256) void cvt_x_kernel(const float* __restrict__ x,
                                                    u16* __restrict__ o) {
    size_t i = (size_t)blockIdx.x * 256 + threadIdx.x;
    const float4* xv = reinterpret_cast<const float4*>(x);
    float4 a = xv[2 * i];
    float4 b = xv[2 * i + 1];
    u16 r[8] = {f2bfu(a.x), f2bfu(a.y), f2bfu(a.z), f2bfu(a.w),
                f2bfu(b.x), f2bfu(b.y), f2bfu(b.z), f2bfu(b.w)};
    *reinterpret_cast<uint4*>(o + i * 8) = *reinterpret_cast<const uint4*>(r);
}

// ---------------- transpose + convert W[K][N] f32 -> Wt[N][K] bf16 ----------------
__global__ __launch_bounds__(256) void trans_w(const float* __restrict__ W,
                                               u16* __restrict__ Wt,
                                               int K, int N) {
    __shared__ __align__(16) float tile[64][72];
    int k0 = blockIdx.y * 64, n0 = blockIdx.x * 64;
    int tid = threadIdx.x;
#pragma unroll
    for (int p = 0; p < 4; ++p) {
        int idx = p * 256 + tid;
        int r = idx >> 4, c = (idx & 15) * 4;
        float4 v = *reinterpret_cast<const float4*>(&W[(size_t)(k0 + r) * N + n0 + c]);
        *reinterpret_cast<float4*>(&tile[r][c]) = v;
    }
    __syncthreads();
#pragma unroll
    for (int p = 0; p < 4; ++p) {
        int idx = p * 256 + tid;
        int nr = idx >> 4, kg = (idx & 15) * 4;
        u16 u[4];
#pragma unroll
        for (int j = 0; j < 4; ++j) u[j] = f2bfu(tile[kg + j][nr]);
        *reinterpret_cast<uint2*>(&Wt[(size_t)(n0 + nr) * K + k0 + kg]) =
            *reinterpret_cast<const uint2*>(u);
    }
}

// ---------------- GEMM: C[M,N] = A[M,K] @ Bt[N,K]^T + bias ----------------
// 1D grid; XCD-aware decode (xcd = bid&7 owns NX/8 n-panels).
// T3-minimum 2-phase: double-buffered LDS, stage(next) issued before compute(cur),
// ONE barrier per K-step (loads fly under MFMA; barrier drains vmcnt+lgkm).
// SCALEQ: pre-scale Q columns (col < 1024) by 0.125*log2(e) for the attn softmax.
template <int F32OUT, int NX, int SCALEQ>
__global__ __launch_bounds__(256) void gemm_bt(const u16* __restrict__ A,
                                               const u16* __restrict__ Bt,
                                               const float* __restrict__ bias,
                                               float* __restrict__ Cf,
                                               u16* __restrict__ Cb,
                                               int M, int N, int K) {
    __shared__ __align__(16) u16 As[2][128 * 32];
    __shared__ __align__(16) u16 Bs[2][128 * 32];
    const int tid = threadIdx.x;
    const int wid = tid >> 6, lane = tid & 63;
    const int lhi = lane >> 4, llo = lane & 15;
    const int xcd = blockIdx.x & 7;
    const int bi = blockIdx.x >> 3;
    const int npx = NX >> 3;
    const int n0 = (xcd * npx + (bi % npx)) * 128;
    const int m0 = (bi / npx) * 128;
    const int wr = wid >> 1, wc = wid & 1;

    f32x4 acc[4][4];
#pragma unroll
    for (int i = 0; i < 4; ++i)
#pragma unroll
        for (int j = 0; j < 4; ++j) acc[i][j] = (f32x4){0.f, 0.f, 0.f, 0.f};

    auto stageAB = [&](int k0, int bsel) {
#pragma unroll
        for (int p = 0; p < 2; ++p) {
            int idx = p * 256 + tid;
            int row = idx >> 2, kc = (idx & 3) * 8;
            gload_lds16(A + (size_t)(m0 + row) * K + k0 + kc,
                        As[bsel] + (size_t)(p * 256 + wid * 64) * 8);
            gload_lds16(Bt + (size_t)(n0 + row) * K + k0 + kc,
                        Bs[bsel] + (size_t)(p * 256 + wid * 64) * 8);
        }
    };

    const int NT = K >> 5;
    stageAB(0, 0);
    __syncthreads();
    int cur = 0;
    for (int t = 0; t < NT; ++t) {
        if (t + 1 < NT) stageAB((t + 1) << 5, cur ^ 1);
        bf16x8 af[4], bfr[4];
#pragma unroll
        for (int mt = 0; mt < 4; ++mt)
            af[mt] = ld_frag(&As[cur][(wr * 64 + mt * 16 + llo) * 32 + lhi * 8]);
#pragma unroll
        for (int nt = 0; nt < 4; ++nt)
            bfr[nt] = ld_frag(&Bs[cur][(wc * 64 + nt * 16 + llo) * 32 + lhi * 8]);
#pragma unroll
        for (int mt = 0; mt < 4; ++mt)
#pragma unroll
            for (int nt = 0; nt < 4; ++nt)
                acc[mt][nt] = __builtin_amdgcn_mfma_f32_16x16x32_bf16(
                    af[mt], bfr[nt], acc[mt][nt], 0, 0, 0);
        __syncthreads();  // drains stage loads; next iter may overwrite As[cur]
        cur ^= 1;
    }

    const float SC2 = 0.18033688f;  // 0.125 * log2(e)
    const int row_base = m0 + wr * 64;
    const int col_base = n0 + wc * 64;
#pragma unroll
    for (int nt = 0; nt < 4; ++nt) {
        int col = col_base + nt * 16 + llo;
        float bv = bias[col];
        const bool doScale = SCALEQ && (col < 1024);
#pragma unroll
        for (int mt = 0; mt < 4; ++mt) {
#pragma unroll
            for (int r = 0; r < 4; ++r) {
                int row = row_base + mt * 16 + lhi * 4 + r;
                float v = acc[mt][nt][r] + bv;
                if (doScale) v *= SC2;
                if (F32OUT)
                    Cf[(size_t)row * N + col] = v;
                else
                    Cb[(size_t)row * N + col] = f2bfu(v);
            }
        }
    }
}

// ---------------- causal flash attention, 8-wave blocks (256 q rows) ----------------
// Q columns pre-scaled by 0.125*log2(e) in gemm1 epilogue -> softmax is exp2(s - m)
// with NO per-tile scaling VALU work.
__global__ __launch_bounds__(512, 2) void attn_kernel(const u16* __restrict__ qkv,
                                                      u16* __restrict__ o) {
    __shared__ __align__(16) u16 smem[17920];  // K:2x4160 @0, Vt:2x4608 @8320; epi 8x2240
    const int bid = blockIdx.x;
    const int qcmap[8] = {7, 6, 5, 4, 0, 1, 2, 3};  // classes (g,g+4) sum to 7
    const int qc = qcmap[bid >> 6];
    const int bh = bid & 63;
    const int b = bh >> 4, h = bh & 15;
    const int tid = threadIdx.x;
    const int wid = tid >> 6, lane = tid & 63;
    const int l31 = lane & 31, lh = lane >> 5;
    const u16* base = qkv + (size_t)b * SEQ_T * (3 * DM);
    const int qrow0 = qc * 256 + wid * 32;
    const int q_abs = qrow0 + l31;
    const int nkv = 4 * qc + 4;

    bf16x8 qf[4];
    {
        const u16* qp = base + (size_t)q_abs * (3 * DM) + h * HD + lh * 8;
#pragma unroll
        for (int km = 0; km < 4; ++km) qf[km] = ld_frag(qp + km * 16);
    }

    f32x16 oac0, oac1;
#pragma unroll
    for (int r = 0; r < 16; ++r) { oac0[r] = 0.f; oac1[r] = 0.f; }
    float m_run = -1e30f, l_run = 0.f;

    uint4 va;
    const int vpr = tid >> 3, vm = tid & 7;  // vpr = V row (0..63), vm = d-slice

    auto stageK = [&](int kb, int bi2) {
        int kv = wid * 8 + (lane >> 3);
        int cl = lane & 7;
        const u16* src = base + (size_t)(kb * 64 + kv) * (3 * DM) + DM + h * HD +
                         ((cl ^ (kv & 7)) * 8);
        gload_lds16(src, smem + bi2 * 4160 + wid * 520);
    };
    auto loadV = [&](int kb) {
        const u16* vp =
            base + (size_t)(kb * 64 + vpr) * (3 * DM) + 2 * DM + h * HD + vm * 8;
        va = *reinterpret_cast<const uint4*>(vp);
    };
    auto writeV = [&](int bi2) {
        u16 ua[8];
        *reinterpret_cast<uint4*>(ua) = va;
        const int sw = (2 * vm) & 7;
        const int col = ((vpr >> 3) ^ sw) * 8 + (vpr & 7);
        u16* vt = smem + 8320 + bi2 * 4608;
#pragma unroll
        for (int j = 0; j < 8; ++j) vt[(vm * 8 + j) * 72 + col] = ua[j];
    };

    loadV(0);
    stageK(0, 0);
    writeV(0);
    __syncthreads();

    const int vsw = (2 * (l31 >> 3)) & 7;
    const int qmax = qrow0 + 31;
    const int krow0 = (l31 >> 3) * 520 + (l31 & 7) * 64;
    const int krow1 = (4 + (l31 >> 3)) * 520 + (l31 & 7) * 64;

    for (int kb = 0; kb < nkv; ++kb) {
        const int cur = kb & 1;
        const bool pre = (kb + 1 < nkv);
        if (pre) { loadV(kb + 1); stageK(kb + 1, cur ^ 1); }

        if (kb * 64 <= qmax) {
            // ---- S^T = K · Q^T  (Q pre-scaled; s already in log2 domain) ----
            f32x16 s0, s1;
#pragma unroll
            for (int r = 0; r < 16; ++r) { s0[r] = 0.f; s1[r] = 0.f; }
            const u16* kbase = smem + cur * 4160;
#pragma unroll
            for (int km = 0; km < 4; ++km) {
                bf16x8 kf = ld_frag(kbase + krow0 + (((km * 2 + lh) ^ (l31 & 7)) * 8));
                s0 = __builtin_amdgcn_mfma_f32_32x32x16_bf16(kf, qf[km], s0, 0, 0, 0);
            }
#pragma unroll
            for (int km = 0; km < 4; ++km) {
                bf16x8 kf = ld_frag(kbase + krow1 + (((km * 2 + lh) ^ (l31 & 7)) * 8));
                s1 = __builtin_amdgcn_mfma_f32_32x32x16_bf16(kf, qf[km], s1, 0, 0, 0);
            }

            // ---- causal mask (diagonal tiles only; no scaling needed) ----
            if (kb * 64 + 63 > qrow0) {
#pragma unroll
                for (int r = 0; r < 16; ++r) {
                    int ka = kb * 64 + (r & 3) + 8 * (r >> 2) + 4 * lh;
                    if (ka > q_abs) s0[r] = -1e30f;
                    if (ka + 32 > q_abs) s1[r] = -1e30f;
                }
            }

            // ---- online softmax, tree reductions, defer-max ----
            float t16[16];
#pragma unroll
            for (int r = 0; r < 16; ++r) t16[r] = fmaxf(s0[r], s1[r]);
#pragma unroll
            for (int r = 0; r < 8; ++r) t16[r] = fmaxf(t16[r], t16[r + 8]);
#pragma unroll
            for (int r = 0; r < 4; ++r) t16[r] = fmaxf(t16[r], t16[r + 4]);
            float pm = fmaxf(fmaxf(t16[0], t16[1]), fmaxf(t16[2], t16[3]));
            pm = fmaxf(pm, __shfl_xor(pm, 32));
            if (!__all(pm - m_run <= 8.f)) {
                const float mnew = fmaxf(m_run, pm);
                const float sc = exp2f(m_run - mnew);
                m_run = mnew;
                l_run *= sc;
#pragma unroll
                for (int r = 0; r < 16; ++r) { oac0[r] *= sc; oac1[r] *= sc; }
            }
            float a16[16];
#pragma unroll
            for (int r = 0; r < 16; ++r) { s0[r] = exp2f(s0[r] - m_run); }
#pragma unroll
            for (int r = 0; r < 16; ++r) { s1[r] = exp2f(s1[r] - m_run); }
#pragma unroll
            for (int r = 0; r < 16; ++r) a16[r] = s0[r] + s1[r];
#pragma unroll
            for (int r = 0; r < 8; ++r) a16[r] += a16[r + 8];
#pragma unroll
            for (int r = 0; r < 4; ++r) a16[r] += a16[r + 4];
            float sum = (a16[0] + a16[1]) + (a16[2] + a16[3]);
            sum += __shfl_xor(sum, 32);
            l_run += sum;

            // ---- P -> bf16 B-fragments: cvt_pk + permlane32_swap ----
            u32t pk0[8], pk1[8];
#pragma unroll
            for (int w = 0; w < 8; ++w) {
                float a0 = s0[2 * w], b0 = s0[2 * w + 1];
                float a1 = s1[2 * w], b1 = s1[2 * w + 1];
                asm("v_cvt_pk_bf16_f32 %0, %1, %2" : "=v"(pk0[w]) : "v"(a0), "v"(b0));
                asm("v_cvt_pk_bf16_f32 %0, %1, %2" : "=v"(pk1[w]) : "v"(a1), "v"(b1));
            }
            asm("v_permlane32_swap_b32 %0, %1" : "+v"(pk0[0]), "+v"(pk0[2]));
            asm("v_permlane32_swap_b32 %0, %1" : "+v"(pk0[1]), "+v"(pk0[3]));
            asm("v_permlane32_swap_b32 %0, %1" : "+v"(pk0[4]), "+v"(pk0[6]));
            asm("v_permlane32_swap_b32 %0, %1" : "+v"(pk0[5]), "+v"(pk0[7]));
            asm("v_permlane32_swap_b32 %0, %1" : "+v"(pk1[0]), "+v"(pk1[2]));
            asm("v_permlane32_swap_b32 %0, %1" : "+v"(pk1[1]), "+v"(pk1[3]));
            asm("v_permlane32_swap_b32 %0, %1" : "+v"(pk1[4]), "+v"(pk1[6]));
            asm("v_permlane32_swap_b32 %0, %1" : "+v"(pk1[5]), "+v"(pk1[7]));
            bf16x8 pf[4];
            {
                uint4 t0 = {pk0[0], pk0[1], pk0[2], pk0[3]};
                uint4 t1 = {pk0[4], pk0[5], pk0[6], pk0[7]};
                uint4 t2 = {pk1[0], pk1[1], pk1[2], pk1[3]};
                uint4 t3 = {pk1[4], pk1[5], pk1[6], pk1[7]};
                pf[0] = __builtin_bit_cast(bf16x8, t0);
                pf[1] = __builtin_bit_cast(bf16x8, t1);
                pf[2] = __builtin_bit_cast(bf16x8, t2);
                pf[3] = __builtin_bit_cast(bf16x8, t3);
            }

            // ---- O^T += V^T · P^T ----
            const u16* vbase = smem + 8320 + cur * 4608;
#pragma unroll
            for (int km = 0; km < 4; ++km) {
                bf16x8 vf = ld_frag(vbase + l31 * 72 + (((km * 2 + lh) ^ vsw) * 8));
                oac0 = __builtin_amdgcn_mfma_f32_32x32x16_bf16(vf, pf[km], oac0, 0, 0, 0);
            }
#pragma unroll
            for (int km = 0; km < 4; ++km) {
                bf16x8 vf = ld_frag(vbase + (32 + l31) * 72 + (((km * 2 + lh) ^ vsw) * 8));
                oac1 = __builtin_amdgcn_mfma_f32_32x32x16_bf16(vf, pf[km], oac1, 0, 0, 0);
            }
        }

        if (pre) writeV(cur ^ 1);
        __syncthreads();
    }

    // ---- epilogue: normalize, transpose O^T->O via LDS, coalesced store ----
    const float inv = 1.f / l_run;
    u16* osh = smem + wid * 2240;  // per-wave [32 q][70 u16]; 8 waves = 17920 u16
#pragma unroll
    for (int r = 0; r < 16; ++r) {
        int dl = (r & 3) + 8 * (r >> 2) + 4 * lh;
        osh[l31 * 70 + dl] = f2bfu(oac0[r] * inv);
        osh[l31 * 70 + 32 + dl] = f2bfu(oac1[r] * inv);
    }
    __syncthreads();
    {
        const u16* rs = osh + l31 * 70 + lh * 32;
        u16* op = o + (size_t)(b * SEQ_T + qrow0 + l31) * DM + h * HD + lh * 32;
        u32t w[16];
#pragma unroll
        for (int i = 0; i < 16; ++i) w[i] = *reinterpret_cast<const u32t*>(rs + i * 2);
#pragma unroll
        for (int i = 0; i < 4; ++i) {
            uint4 t = {w[4 * i], w[4 * i + 1], w[4 * i + 2], w[4 * i + 3]};
            *reinterpret_cast<uint4*>(op + 8 * i) = t;
        }
    }
}

extern "C" void kernel_launch(void* const* d_in, const int* in_sizes, int n_in,
                              void* d_out, int out_size, void* d_ws, size_t ws_size,
                              hipStream_t stream) {
    const float* x = (const float*)d_in[0];
    const float* Wqkv = (const float*)d_in[1];
    const float* bqkv = (const float*)d_in[2];
    const float* Wproj = (const float*)d_in[3];
    const float* bproj = (const float*)d_in[4];
    float* out = (float*)d_out;
    char* ws = (char*)d_ws;

    u16* xb   = (u16*)(ws);                         // 16,777,216 B
    u16* wtq  = (u16*)(ws + 16777216);              //  6,291,456 B
    u16* wtp  = (u16*)(ws + 23068672);              //  2,097,152 B
    u16* qkvb = (u16*)(ws + 25165824);              // 50,331,648 B
    u16* ob   = (u16*)(ws + 75497472);              // 16,777,216 B

    cvt_x_kernel<<<4096, 256, 0, stream>>>(x, xb);
    trans_w<<<dim3(3072 / 64, 1024 / 64), 256, 0, stream>>>(Wqkv, wtq, 1024, 3072);
    trans_w<<<dim3(1024 / 64, 1024 / 64), 256, 0, stream>>>(Wproj, wtp, 1024, 1024);

    gemm_bt<0, 24, 1><<<1536, 256, 0, stream>>>(
        xb, wtq, bqkv, nullptr, qkvb, 8192, 3072, 1024);

    attn_kernel<<<512, 512, 0, stream>>>(qkvb, ob);

    gemm_bt<1, 8, 0><<<512, 256, 0, stream>>>(
        ob, wtp, bproj, out, nullptr, 8192, 1024, 1024);
}

// Round 16
// 212.026 us; speedup vs baseline: 1.9803x; 1.0191x over previous
//
#include <hip/hip_runtime.h>
#include <hip/hip_bf16.h>
#include <stdint.h>

using u16 = unsigned short;
using u32t = unsigned int;
typedef __bf16 bf16x8 __attribute__((ext_vector_type(8)));
typedef float f32x4 __attribute__((ext_vector_type(4)));
typedef float f32x16 __attribute__((ext_vector_type(16)));

#define SEQ_T 2048
#define DM 1024
#define NH 16
#define HD 64
#define NB 4

__device__ inline u16 f2bfu(float f) {
    __hip_bfloat16 h = __float2bfloat16(f);
    return __builtin_bit_cast(u16, h);
}

__device__ inline bf16x8 ld_frag(const u16* p) {
    return __builtin_bit_cast(bf16x8, *reinterpret_cast<const uint4*>(p));
}

__device__ inline void gload_lds16(const u16* g, u16* l) {
    __builtin_amdgcn_global_load_lds(
        (const __attribute__((address_space(1))) void*)g,
        (__attribute__((address_space(3))) void*)l, 16, 0, 0);
}

// ---------------- convert x (f32 -> bf16), 8 elems/thread ----------------
__global__ __launch_bounds__(256) void cvt_x_kernel(const float* __restrict__ x,
                                                    u16* __restrict__ o) {
    size_t i = (size_t)blockIdx.x * 256 + threadIdx.x;
    const float4* xv = reinterpret_cast<const float4*>(x);
    float4 a = xv[2 * i];
    float4 b = xv[2 * i + 1];
    u16 r[8] = {f2bfu(a.x), f2bfu(a.y), f2bfu(a.z), f2bfu(a.w),
                f2bfu(b.x), f2bfu(b.y), f2bfu(b.z), f2bfu(b.w)};
    *reinterpret_cast<uint4*>(o + i * 8) = *reinterpret_cast<const uint4*>(r);
}

// ---------------- transpose + convert W[K][N] f32 -> Wt[N][K] bf16 ----------------
__global__ __launch_bounds__(256) void trans_w(const float* __restrict__ W,
                                               u16* __restrict__ Wt,
                                               int K, int N) {
    __shared__ __align__(16) float tile[64][72];
    int k0 = blockIdx.y * 64, n0 = blockIdx.x * 64;
    int tid = threadIdx.x;
#pragma unroll
    for (int p = 0; p < 4; ++p) {
        int idx = p * 256 + tid;
        int r = idx >> 4, c = (idx & 15) * 4;
        float4 v = *reinterpret_cast<const float4*>(&W[(size_t)(k0 + r) * N + n0 + c]);
        *reinterpret_cast<float4*>(&tile[r][c]) = v;
    }
    __syncthreads();
#pragma unroll
    for (int p = 0; p < 4; ++p) {
        int idx = p * 256 + tid;
        int nr = idx >> 4, kg = (idx & 15) * 4;
        u16 u[4];
#pragma unroll
        for (int j = 0; j < 4; ++j) u[j] = f2bfu(tile[kg + j][nr]);
        *reinterpret_cast<uint2*>(&Wt[(size_t)(n0 + nr) * K + k0 + kg]) =
            *reinterpret_cast<const uint2*>(u);
    }
}

// ---------------- GEMM: C[M,N] = A[M,K] @ Bt[N,K]^T + bias ----------------
// 2-phase double-buffered; XCD-aware decode; SCALEQ pre-scales Q cols by 0.125*log2e.
template <int F32OUT, int NX, int SCALEQ>
__global__ __launch_bounds__(256) void gemm_bt(const u16* __restrict__ A,
                                               const u16* __restrict__ Bt,
                                               const float* __restrict__ bias,
                                               float* __restrict__ Cf,
                                               u16* __restrict__ Cb,
                                               int M, int N, int K) {
    __shared__ __align__(16) u16 As[2][128 * 32];
    __shared__ __align__(16) u16 Bs[2][128 * 32];
    const int tid = threadIdx.x;
    const int wid = tid >> 6, lane = tid & 63;
    const int lhi = lane >> 4, llo = lane & 15;
    const int xcd = blockIdx.x & 7;
    const int bi = blockIdx.x >> 3;
    const int npx = NX >> 3;
    const int n0 = (xcd * npx + (bi % npx)) * 128;
    const int m0 = (bi / npx) * 128;
    const int wr = wid >> 1, wc = wid & 1;

    f32x4 acc[4][4];
#pragma unroll
    for (int i = 0; i < 4; ++i)
#pragma unroll
        for (int j = 0; j < 4; ++j) acc[i][j] = (f32x4){0.f, 0.f, 0.f, 0.f};

    auto stageAB = [&](int k0, int bsel) {
#pragma unroll
        for (int p = 0; p < 2; ++p) {
            int idx = p * 256 + tid;
            int row = idx >> 2, kc = (idx & 3) * 8;
            gload_lds16(A + (size_t)(m0 + row) * K + k0 + kc,
                        As[bsel] + (size_t)(p * 256 + wid * 64) * 8);
            gload_lds16(Bt + (size_t)(n0 + row) * K + k0 + kc,
                        Bs[bsel] + (size_t)(p * 256 + wid * 64) * 8);
        }
    };

    const int NT = K >> 5;
    stageAB(0, 0);
    __syncthreads();
    int cur = 0;
    for (int t = 0; t < NT; ++t) {
        if (t + 1 < NT) stageAB((t + 1) << 5, cur ^ 1);
        bf16x8 af[4], bfr[4];
#pragma unroll
        for (int mt = 0; mt < 4; ++mt)
            af[mt] = ld_frag(&As[cur][(wr * 64 + mt * 16 + llo) * 32 + lhi * 8]);
#pragma unroll
        for (int nt = 0; nt < 4; ++nt)
            bfr[nt] = ld_frag(&Bs[cur][(wc * 64 + nt * 16 + llo) * 32 + lhi * 8]);
#pragma unroll
        for (int mt = 0; mt < 4; ++mt)
#pragma unroll
            for (int nt = 0; nt < 4; ++nt)
                acc[mt][nt] = __builtin_amdgcn_mfma_f32_16x16x32_bf16(
                    af[mt], bfr[nt], acc[mt][nt], 0, 0, 0);
        __syncthreads();
        cur ^= 1;
    }

    const float SC2 = 0.18033688f;  // 0.125 * log2(e)
    const int row_base = m0 + wr * 64;
    const int col_base = n0 + wc * 64;
#pragma unroll
    for (int nt = 0; nt < 4; ++nt) {
        int col = col_base + nt * 16 + llo;
        float bv = bias[col];
        const bool doScale = SCALEQ && (col < 1024);
#pragma unroll
        for (int mt = 0; mt < 4; ++mt) {
#pragma unroll
            for (int r = 0; r < 4; ++r) {
                int row = row_base + mt * 16 + lhi * 4 + r;
                float v = acc[mt][nt][r] + bv;
                if (doScale) v *= SC2;
                if (F32OUT)
                    Cf[(size_t)row * N + col] = v;
                else
                    Cb[(size_t)row * N + col] = f2bfu(v);
            }
        }
    }
}

// ---------------- causal flash attention, 8-wave blocks, KVBLK=128 ----------------
// Block: 512 thr (8 waves) x 256 q rows; grid 512 = 2 blocks/CU.
// Each iteration stages 128 kv rows (K chunked-520, Vt stride-136 chunk-XOR swizzled)
// and computes two 64-kv sub-steps -> HALF the barrier/drain events of KVBLK=64.
__global__ __launch_bounds__(512, 2) void attn_kernel(const u16* __restrict__ qkv,
                                                      u16* __restrict__ o) {
    __shared__ __align__(16) u16 smem[34048];  // K:2x8320 @0, Vt:2x8704 @16640
    const int bid = blockIdx.x;
    const int qcmap[8] = {7, 6, 5, 4, 0, 1, 2, 3};  // CU pairs sum nkv2 = 18
    const int qc = qcmap[bid >> 6];
    const int bh = bid & 63;
    const int b = bh >> 4, h = bh & 15;
    const int tid = threadIdx.x;
    const int wid = tid >> 6, lane = tid & 63;
    const int l31 = lane & 31, lh = lane >> 5;
    const u16* base = qkv + (size_t)b * SEQ_T * (3 * DM);
    const int qrow0 = qc * 256 + wid * 32;
    const int q_abs = qrow0 + l31;
    const int nkv2 = 2 * qc + 2;  // 128-kv tiles

    bf16x8 qf[4];
    {
        const u16* qp = base + (size_t)q_abs * (3 * DM) + h * HD + lh * 8;
#pragma unroll
        for (int km = 0; km < 4; ++km) qf[km] = ld_frag(qp + km * 16);
    }

    f32x16 oac0, oac1;
#pragma unroll
    for (int r = 0; r < 16; ++r) { oac0[r] = 0.f; oac1[r] = 0.f; }
    float m_run = -1e30f, l_run = 0.f;

    uint4 va, vb;
    const int vpr = tid >> 3, vm = tid & 7;  // V row-pair (0..63 -> rows 2v,2v+1), d-slice

    auto stageK = [&](int kb2, int bi2) {
#pragma unroll
        for (int p = 0; p < 2; ++p) {
            int kv = p * 64 + wid * 8 + (lane >> 3);
            int cl = lane & 7;
            const u16* src = base + (size_t)(kb2 * 128 + kv) * (3 * DM) + DM + h * HD +
                             ((cl ^ (kv & 7)) * 8);
            gload_lds16(src, smem + bi2 * 8320 + (p * 8 + wid) * 520);
        }
    };
    auto loadV = [&](int kb2) {
        const u16* vp =
            base + (size_t)(kb2 * 128 + 2 * vpr) * (3 * DM) + 2 * DM + h * HD + vm * 8;
        va = *reinterpret_cast<const uint4*>(vp);
        vb = *reinterpret_cast<const uint4*>(vp + 3 * DM);
    };
    auto writeV = [&](int bi2) {  // Vt[d][kv], rows 136 u16, 16-chunk XOR swizzle
        u16 ua[8], ub[8];
        *reinterpret_cast<uint4*>(ua) = va;
        *reinterpret_cast<uint4*>(ub) = vb;
        const int cb = vpr >> 2, off = 2 * (vpr & 3);  // chunk 0..15, intra-chunk pair
        const int sw = (2 * vm) & 7;                   // sw(d), d>>3 == vm
        u16* vt = smem + 16640 + bi2 * 8704;
#pragma unroll
        for (int j = 0; j < 8; ++j) {
            int d = vm * 8 + j;
            u32t val = (u32t)ua[j] | ((u32t)ub[j] << 16);
            *reinterpret_cast<u32t*>(vt + d * 136 + ((cb ^ sw) * 8) + off) = val;
        }
    };

    loadV(0);
    stageK(0, 0);
    writeV(0);
    __syncthreads();

    const int vsw = (2 * (l31 >> 3)) & 7;
    const int qmax = qrow0 + 31;
    const int krow0 = (l31 >> 3) * 520 + (l31 & 7) * 64;
    const int krow1 = (4 + (l31 >> 3)) * 520 + (l31 & 7) * 64;

    for (int kb2 = 0; kb2 < nkv2; ++kb2) {
        const int cur = kb2 & 1;
        const bool pre = (kb2 + 1 < nkv2);
        if (pre) { loadV(kb2 + 1); stageK(kb2 + 1, cur ^ 1); }

#pragma unroll
        for (int s = 0; s < 2; ++s) {
            const int kv0 = kb2 * 128 + s * 64;
            if (kv0 > qmax) continue;
            // ---- S^T = K · Q^T (Q pre-scaled into log2 domain) ----
            f32x16 s0, s1;
#pragma unroll
            for (int r = 0; r < 16; ++r) { s0[r] = 0.f; s1[r] = 0.f; }
            const u16* kbase = smem + cur * 8320 + s * 4160;
#pragma unroll
            for (int km = 0; km < 4; ++km) {
                bf16x8 kf = ld_frag(kbase + krow0 + (((km * 2 + lh) ^ (l31 & 7)) * 8));
                s0 = __builtin_amdgcn_mfma_f32_32x32x16_bf16(kf, qf[km], s0, 0, 0, 0);
            }
#pragma unroll
            for (int km = 0; km < 4; ++km) {
                bf16x8 kf = ld_frag(kbase + krow1 + (((km * 2 + lh) ^ (l31 & 7)) * 8));
                s1 = __builtin_amdgcn_mfma_f32_32x32x16_bf16(kf, qf[km], s1, 0, 0, 0);
            }

            // ---- causal mask (diagonal sub-tiles only) ----
            if (kv0 + 63 > qrow0) {
#pragma unroll
                for (int r = 0; r < 16; ++r) {
                    int ka = kv0 + (r & 3) + 8 * (r >> 2) + 4 * lh;
                    if (ka > q_abs) s0[r] = -1e30f;
                    if (ka + 32 > q_abs) s1[r] = -1e30f;
                }
            }

            // ---- online softmax, tree reductions, defer-max ----
            float t16[16];
#pragma unroll
            for (int r = 0; r < 16; ++r) t16[r] = fmaxf(s0[r], s1[r]);
#pragma unroll
            for (int r = 0; r < 8; ++r) t16[r] = fmaxf(t16[r], t16[r + 8]);
#pragma unroll
            for (int r = 0; r < 4; ++r) t16[r] = fmaxf(t16[r], t16[r + 4]);
            float pm = fmaxf(fmaxf(t16[0], t16[1]), fmaxf(t16[2], t16[3]));
            pm = fmaxf(pm, __shfl_xor(pm, 32));
            if (!__all(pm - m_run <= 8.f)) {
                const float mnew = fmaxf(m_run, pm);
                const float sc = exp2f(m_run - mnew);
                m_run = mnew;
                l_run *= sc;
#pragma unroll
                for (int r = 0; r < 16; ++r) { oac0[r] *= sc; oac1[r] *= sc; }
            }
            float a16[16];
#pragma unroll
            for (int r = 0; r < 16; ++r) { s0[r] = exp2f(s0[r] - m_run); }
#pragma unroll
            for (int r = 0; r < 16; ++r) { s1[r] = exp2f(s1[r] - m_run); }
#pragma unroll
            for (int r = 0; r < 16; ++r) a16[r] = s0[r] + s1[r];
#pragma unroll
            for (int r = 0; r < 8; ++r) a16[r] += a16[r + 8];
#pragma unroll
            for (int r = 0; r < 4; ++r) a16[r] += a16[r + 4];
            float sum = (a16[0] + a16[1]) + (a16[2] + a16[3]);
            sum += __shfl_xor(sum, 32);
            l_run += sum;

            // ---- P -> bf16 B-fragments: cvt_pk + permlane32_swap ----
            u32t pk0[8], pk1[8];
#pragma unroll
            for (int w = 0; w < 8; ++w) {
                float a0 = s0[2 * w], b0 = s0[2 * w + 1];
                float a1 = s1[2 * w], b1 = s1[2 * w + 1];
                asm("v_cvt_pk_bf16_f32 %0, %1, %2" : "=v"(pk0[w]) : "v"(a0), "v"(b0));
                asm("v_cvt_pk_bf16_f32 %0, %1, %2" : "=v"(pk1[w]) : "v"(a1), "v"(b1));
            }
            asm("v_permlane32_swap_b32 %0, %1" : "+v"(pk0[0]), "+v"(pk0[2]));
            asm("v_permlane32_swap_b32 %0, %1" : "+v"(pk0[1]), "+v"(pk0[3]));
            asm("v_permlane32_swap_b32 %0, %1" : "+v"(pk0[4]), "+v"(pk0[6]));
            asm("v_permlane32_swap_b32 %0, %1" : "+v"(pk0[5]), "+v"(pk0[7]));
            asm("v_permlane32_swap_b32 %0, %1" : "+v"(pk1[0]), "+v"(pk1[2]));
            asm("v_permlane32_swap_b32 %0, %1" : "+v"(pk1[1]), "+v"(pk1[3]));
            asm("v_permlane32_swap_b32 %0, %1" : "+v"(pk1[4]), "+v"(pk1[6]));
            asm("v_permlane32_swap_b32 %0, %1" : "+v"(pk1[5]), "+v"(pk1[7]));
            bf16x8 pf[4];
            {
                uint4 t0 = {pk0[0], pk0[1], pk0[2], pk0[3]};
                uint4 t1 = {pk0[4], pk0[5], pk0[6], pk0[7]};
                uint4 t2 = {pk1[0], pk1[1], pk1[2], pk1[3]};
                uint4 t3 = {pk1[4], pk1[5], pk1[6], pk1[7]};
                pf[0] = __builtin_bit_cast(bf16x8, t0);
                pf[1] = __builtin_bit_cast(bf16x8, t1);
                pf[2] = __builtin_bit_cast(bf16x8, t2);
                pf[3] = __builtin_bit_cast(bf16x8, t3);
            }

            // ---- O^T += V^T · P^T ----
            const u16* vbase = smem + 16640 + cur * 8704;
#pragma unroll
            for (int km = 0; km < 4; ++km) {
                bf16x8 vf = ld_frag(vbase + l31 * 136 +
                                    ((s * 8 + ((km * 2 + lh) ^ vsw)) * 8));
                oac0 = __builtin_amdgcn_mfma_f32_32x32x16_bf16(vf, pf[km], oac0, 0, 0, 0);
            }
#pragma unroll
            for (int km = 0; km < 4; ++km) {
                bf16x8 vf = ld_frag(vbase + (32 + l31) * 136 +
                                    ((s * 8 + ((km * 2 + lh) ^ vsw)) * 8));
                oac1 = __builtin_amdgcn_mfma_f32_32x32x16_bf16(vf, pf[km], oac1, 0, 0, 0);
            }
        }

        if (pre) writeV(cur ^ 1);
        __syncthreads();
    }

    // ---- epilogue: normalize, transpose O^T->O via LDS, coalesced store ----
    const float inv = 1.f / l_run;
    u16* osh = smem + wid * 2240;  // per-wave [32 q][70 u16]; 8 waves = 17920 u16
#pragma unroll
    for (int r = 0; r < 16; ++r) {
        int dl = (r & 3) + 8 * (r >> 2) + 4 * lh;
        osh[l31 * 70 + dl] = f2bfu(oac0[r] * inv);
        osh[l31 * 70 + 32 + dl] = f2bfu(oac1[r] * inv);
    }
    __syncthreads();
    {
        const u16* rs = osh + l31 * 70 + lh * 32;
        u16* op = o + (size_t)(b * SEQ_T + qrow0 + l31) * DM + h * HD + lh * 32;
        u32t w[16];
#pragma unroll
        for (int i = 0; i < 16; ++i) w[i] = *reinterpret_cast<const u32t*>(rs + i * 2);
#pragma unroll
        for (int i = 0; i < 4; ++i) {
            uint4 t = {w[4 * i], w[4 * i + 1], w[4 * i + 2], w[4 * i + 3]};
            *reinterpret_cast<uint4*>(op + 8 * i) = t;
        }
    }
}

extern "C" void kernel_launch(void* const* d_in, const int* in_sizes, int n_in,
                              void* d_out, int out_size, void* d_ws, size_t ws_size,
                              hipStream_t stream) {
    const float* x = (const float*)d_in[0];
    const float* Wqkv = (const float*)d_in[1];
    const float* bqkv = (const float*)d_in[2];
    const float* Wproj = (const float*)d_in[3];
    const float* bproj = (const float*)d_in[4];
    float* out = (float*)d_out;
    char* ws = (char*)d_ws;

    u16* xb   = (u16*)(ws);                         // 16,777,216 B
    u16* wtq  = (u16*)(ws + 16777216);              //  6,291,456 B
    u16* wtp  = (u16*)(ws + 23068672);              //  2,097,152 B
    u16* qkvb = (u16*)(ws + 25165824);              // 50,331,648 B
    u16* ob   = (u16*)(ws + 75497472);              // 16,777,216 B

    cvt_x_kernel<<<4096, 256, 0, stream>>>(x, xb);
    trans_w<<<dim3(3072 / 64, 1024 / 64), 256, 0, stream>>>(Wqkv, wtq, 1024, 3072);
    trans_w<<<dim3(1024 / 64, 1024 / 64), 256, 0, stream>>>(Wproj, wtp, 1024, 1024);

    gemm_bt<0, 24, 1><<<1536, 256, 0, stream>>>(
        xb, wtq, bqkv, nullptr, qkvb, 8192, 3072, 1024);

    attn_kernel<<<512, 512, 0, stream>>>(qkvb, ob);

    gemm_bt<1, 8, 0><<<512, 256, 0, stream>>>(
        ob, wtp, bproj, out, nullptr, 8192, 1024, 1024);
}

// Round 17
// 207.424 us; speedup vs baseline: 2.0242x; 1.0222x over previous
//
#include <hip/hip_runtime.h>
#include <hip/hip_bf16.h>
#include <stdint.h>

using u16 = unsigned short;
using u32t = unsigned int;
typedef __bf16 bf16x8 __attribute__((ext_vector_type(8)));
typedef float f32x4 __attribute__((ext_vector_type(4)));
typedef float f32x16 __attribute__((ext_vector_type(16)));

#define SEQ_T 2048
#define DM 1024
#define NH 16
#define HD 64
#define NB 4

__device__ inline u16 f2bfu(float f) {
    __hip_bfloat16 h = __float2bfloat16(f);
    return __builtin_bit_cast(u16, h);
}

__device__ inline bf16x8 ld_frag(const u16* p) {
    return __builtin_bit_cast(bf16x8, *reinterpret_cast<const uint4*>(p));
}

__device__ inline void gload_lds16(const u16* g, u16* l) {
    __builtin_amdgcn_global_load_lds(
        (const __attribute__((address_space(1))) void*)g,
        (__attribute__((address_space(3))) void*)l, 16, 0, 0);
}

// ---------------- convert x (f32 -> bf16), 8 elems/thread ----------------
__global__ __launch_bounds__(256) void cvt_x_kernel(const float* __restrict__ x,
                                                    u16* __restrict__ o) {
    size_t i = (size_t)blockIdx.x * 256 + threadIdx.x;
    const float4* xv = reinterpret_cast<const float4*>(x);
    float4 a = xv[2 * i];
    float4 b = xv[2 * i + 1];
    u16 r[8] = {f2bfu(a.x), f2bfu(a.y), f2bfu(a.z), f2bfu(a.w),
                f2bfu(b.x), f2bfu(b.y), f2bfu(b.z), f2bfu(b.w)};
    *reinterpret_cast<uint4*>(o + i * 8) = *reinterpret_cast<const uint4*>(r);
}

// ---------------- transpose + convert W[K][N] f32 -> Wt[N][K] bf16 ----------------
__global__ __launch_bounds__(256) void trans_w(const float* __restrict__ W,
                                               u16* __restrict__ Wt,
                                               int K, int N) {
    __shared__ __align__(16) float tile[64][72];
    int k0 = blockIdx.y * 64, n0 = blockIdx.x * 64;
    int tid = threadIdx.x;
#pragma unroll
    for (int p = 0; p < 4; ++p) {
        int idx = p * 256 + tid;
        int r = idx >> 4, c = (idx & 15) * 4;
        float4 v = *reinterpret_cast<const float4*>(&W[(size_t)(k0 + r) * N + n0 + c]);
        *reinterpret_cast<float4*>(&tile[r][c]) = v;
    }
    __syncthreads();
#pragma unroll
    for (int p = 0; p < 4; ++p) {
        int idx = p * 256 + tid;
        int nr = idx >> 4, kg = (idx & 15) * 4;
        u16 u[4];
#pragma unroll
        for (int j = 0; j < 4; ++j) u[j] = f2bfu(tile[kg + j][nr]);
        *reinterpret_cast<uint2*>(&Wt[(size_t)(n0 + nr) * K + k0 + kg]) =
            *reinterpret_cast<const uint2*>(u);
    }
}

// ---------------- deep-pipelined GEMM: C[M,N] = A[M,K] @ Bt[N,K]^T + bias ----
// BM=256 BN=128 BK=64, 512 thr (8 waves: wm=wid>>1? no: 4M x 2N), ring-3 LDS
// (48KB/K-tile x 3 = 144KB). Stage leads consumption by 2 K-tiles; counted
// vmcnt(6) once per K-tile (never 0 until the last); raw s_barrier per phase
// (2 phases/K-tile, 16 MFMA each); chunk-XOR swizzle (^row&7) both sides.
template <int F32OUT, int SCALEQ>
__global__ __launch_bounds__(512, 2) void gemm_p3(const u16* __restrict__ A,
                                                  const u16* __restrict__ Bt,
                                                  const float* __restrict__ bias,
                                                  float* __restrict__ Cf,
                                                  u16* __restrict__ Cb,
                                                  int M, int N, int K) {
    __shared__ __align__(16) u16 smem[73728];  // 3 bufs x (A 16384 + B 8192) u16
    const int tid = threadIdx.x;
    const int wid = tid >> 6, lane = tid & 63;
    const int llo = lane & 15, lhi = lane >> 4;
    const int wm = wid >> 1, wn = wid & 1;  // 4 M-waves x 2 N-waves
    const int cpx = gridDim.x >> 3;
    const int swz = (blockIdx.x & 7) * cpx + (blockIdx.x >> 3);
    const int nb = N >> 7;
    const int m0 = (swz / nb) << 8, n0 = (swz % nb) << 7;
    const int T = K >> 6;

    f32x4 acc[4][4];
#pragma unroll
    for (int i = 0; i < 4; ++i)
#pragma unroll
        for (int j = 0; j < 4; ++j) acc[i][j] = (f32x4){0.f, 0.f, 0.f, 0.f};

    // stage part p (0/1) of K-tile t2 into buffer base sb (u16 offset).
    // A: rows p*128..p*128+127 (2 loads/thread); B: cols p*64..p*64+63 (1 load).
    auto stage2 = [&](int t2, int p, int sb) {
        const int kbase = t2 << 6;
#pragma unroll
        for (int j = 0; j < 2; ++j) {
            int c = (j * 8 + wid) * 64 + lane;
            int row = c >> 3, cc = c & 7;
            int kc = cc ^ (row & 7);
            const u16* src = A + (size_t)(m0 + p * 128 + row) * K + kbase + kc * 8;
            gload_lds16(src, smem + sb + p * 8192 + (j * 8 + wid) * 512);
        }
        {
            int c = wid * 64 + lane;
            int row = c >> 3, cc = c & 7;
            int kc = cc ^ (row & 7);
            const u16* src = Bt + (size_t)(n0 + p * 64 + row) * K + kbase + kc * 8;
            gload_lds16(src, smem + sb + 16384 + p * 4096 + wid * 512);
        }
    };

    // prologue: stage K-tiles 0 and 1 (12 loads/thread)
    stage2(0, 0, 0);
    stage2(0, 1, 0);
    stage2(1, 0, 24576);
    stage2(1, 1, 24576);

    const int l7 = llo & 7;
    for (int t = 0; t < T; ++t) {
        const int cb = (t % 3) * 24576;
        const u16* Ab = smem + cb;
        const u16* Bb = smem + cb + 16384;
        const int sb = ((t + 2) % 3) * 24576;
        const bool pre = (t + 2 < T);
        bf16x8 bfr[4][2];
#pragma unroll
        for (int p = 0; p < 2; ++p) {
            if (p == 0) {
                if (t == T - 1)
                    asm volatile("s_waitcnt vmcnt(0)" ::: "memory");
                else
                    asm volatile("s_waitcnt vmcnt(6)" ::: "memory");
                __builtin_amdgcn_sched_barrier(0);
            }
            __builtin_amdgcn_s_barrier();
            __builtin_amdgcn_sched_barrier(0);
            if (p == 0) {
#pragma unroll
                for (int nf = 0; nf < 4; ++nf) {
                    int lc = wn * 64 + nf * 16 + llo;
#pragma unroll
                    for (int ks = 0; ks < 2; ++ks)
                        bfr[nf][ks] =
                            ld_frag(Bb + lc * 64 + (((ks * 4 + lhi) ^ l7) * 8));
                }
            }
            bf16x8 af[2][2];
#pragma unroll
            for (int j = 0; j < 2; ++j) {
                int row = wm * 64 + (p * 2 + j) * 16 + llo;
#pragma unroll
                for (int ks = 0; ks < 2; ++ks)
                    af[j][ks] = ld_frag(Ab + row * 64 + (((ks * 4 + lhi) ^ l7) * 8));
            }
            if (pre) stage2(t + 2, p, sb);
            __builtin_amdgcn_s_setprio(1);
#pragma unroll
            for (int j = 0; j < 2; ++j)
#pragma unroll
                for (int nf = 0; nf < 4; ++nf)
#pragma unroll
                    for (int ks = 0; ks < 2; ++ks)
                        acc[p * 2 + j][nf] = __builtin_amdgcn_mfma_f32_16x16x32_bf16(
                            af[j][ks], bfr[nf][ks], acc[p * 2 + j][nf], 0, 0, 0);
            __builtin_amdgcn_s_setprio(0);
        }
    }

    const float SC2 = 0.18033688f;  // 0.125 * log2(e)
    const int row_base = m0 + wm * 64;
    const int col_base = n0 + wn * 64;
#pragma unroll
    for (int nf = 0; nf < 4; ++nf) {
        int col = col_base + nf * 16 + llo;
        float bv = bias[col];
        const bool doScale = SCALEQ && (col < 1024);
#pragma unroll
        for (int mf = 0; mf < 4; ++mf) {
#pragma unroll
            for (int r = 0; r < 4; ++r) {
                int row = row_base + mf * 16 + lhi * 4 + r;
                float v = acc[mf][nf][r] + bv;
                if (doScale) v *= SC2;
                if (F32OUT)
                    Cf[(size_t)row * N + col] = v;
                else
                    Cb[(size_t)row * N + col] = f2bfu(v);
            }
        }
    }
}

// ---------------- causal flash attention, 8-wave blocks, KVBLK=128 ----------------
__global__ __launch_bounds__(512, 2) void attn_kernel(const u16* __restrict__ qkv,
                                                      u16* __restrict__ o) {
    __shared__ __align__(16) u16 smem[34048];  // K:2x8320 @0, Vt:2x8704 @16640
    const int bid = blockIdx.x;
    const int qcmap[8] = {7, 6, 5, 4, 0, 1, 2, 3};
    const int qc = qcmap[bid >> 6];
    const int bh = bid & 63;
    const int b = bh >> 4, h = bh & 15;
    const int tid = threadIdx.x;
    const int wid = tid >> 6, lane = tid & 63;
    const int l31 = lane & 31, lh = lane >> 5;
    const u16* base = qkv + (size_t)b * SEQ_T * (3 * DM);
    const int qrow0 = qc * 256 + wid * 32;
    const int q_abs = qrow0 + l31;
    const int nkv2 = 2 * qc + 2;

    bf16x8 qf[4];
    {
        const u16* qp = base + (size_t)q_abs * (3 * DM) + h * HD + lh * 8;
#pragma unroll
        for (int km = 0; km < 4; ++km) qf[km] = ld_frag(qp + km * 16);
    }

    f32x16 oac0, oac1;
#pragma unroll
    for (int r = 0; r < 16; ++r) { oac0[r] = 0.f; oac1[r] = 0.f; }
    float m_run = -1e30f, l_run = 0.f;

    uint4 va, vb;
    const int vpr = tid >> 3, vm = tid & 7;

    auto stageK = [&](int kb2, int bi2) {
#pragma unroll
        for (int p = 0; p < 2; ++p) {
            int kv = p * 64 + wid * 8 + (lane >> 3);
            int cl = lane & 7;
            const u16* src = base + (size_t)(kb2 * 128 + kv) * (3 * DM) + DM + h * HD +
                             ((cl ^ (kv & 7)) * 8);
            gload_lds16(src, smem + bi2 * 8320 + (p * 8 + wid) * 520);
        }
    };
    auto loadV = [&](int kb2) {
        const u16* vp =
            base + (size_t)(kb2 * 128 + 2 * vpr) * (3 * DM) + 2 * DM + h * HD + vm * 8;
        va = *reinterpret_cast<const uint4*>(vp);
        vb = *reinterpret_cast<const uint4*>(vp + 3 * DM);
    };
    auto writeV = [&](int bi2) {
        u16 ua[8], ub[8];
        *reinterpret_cast<uint4*>(ua) = va;
        *reinterpret_cast<uint4*>(ub) = vb;
        const int cbk = vpr >> 2, off = 2 * (vpr & 3);
        const int sw = (2 * vm) & 7;
        u16* vt = smem + 16640 + bi2 * 8704;
#pragma unroll
        for (int j = 0; j < 8; ++j) {
            int d = vm * 8 + j;
            u32t val = (u32t)ua[j] | ((u32t)ub[j] << 16);
            *reinterpret_cast<u32t*>(vt + d * 136 + ((cbk ^ sw) * 8) + off) = val;
        }
    };

    loadV(0);
    stageK(0, 0);
    writeV(0);
    __syncthreads();

    const int vsw = (2 * (l31 >> 3)) & 7;
    const int qmax = qrow0 + 31;
    const int krow0 = (l31 >> 3) * 520 + (l31 & 7) * 64;
    const int krow1 = (4 + (l31 >> 3)) * 520 + (l31 & 7) * 64;

    for (int kb2 = 0; kb2 < nkv2; ++kb2) {
        const int cur = kb2 & 1;
        const bool pre = (kb2 + 1 < nkv2);
        if (pre) { loadV(kb2 + 1); stageK(kb2 + 1, cur ^ 1); }

#pragma unroll
        for (int s = 0; s < 2; ++s) {
            const int kv0 = kb2 * 128 + s * 64;
            if (kv0 > qmax) continue;
            f32x16 s0, s1;
#pragma unroll
            for (int r = 0; r < 16; ++r) { s0[r] = 0.f; s1[r] = 0.f; }
            const u16* kbase = smem + cur * 8320 + s * 4160;
#pragma unroll
            for (int km = 0; km < 4; ++km) {
                bf16x8 kf = ld_frag(kbase + krow0 + (((km * 2 + lh) ^ (l31 & 7)) * 8));
                s0 = __builtin_amdgcn_mfma_f32_32x32x16_bf16(kf, qf[km], s0, 0, 0, 0);
            }
#pragma unroll
            for (int km = 0; km < 4; ++km) {
                bf16x8 kf = ld_frag(kbase + krow1 + (((km * 2 + lh) ^ (l31 & 7)) * 8));
                s1 = __builtin_amdgcn_mfma_f32_32x32x16_bf16(kf, qf[km], s1, 0, 0, 0);
            }

            if (kv0 + 63 > qrow0) {
#pragma unroll
                for (int r = 0; r < 16; ++r) {
                    int ka = kv0 + (r & 3) + 8 * (r >> 2) + 4 * lh;
                    if (ka > q_abs) s0[r] = -1e30f;
                    if (ka + 32 > q_abs) s1[r] = -1e30f;
                }
            }

            float t16[16];
#pragma unroll
            for (int r = 0; r < 16; ++r) t16[r] = fmaxf(s0[r], s1[r]);
#pragma unroll
            for (int r = 0; r < 8; ++r) t16[r] = fmaxf(t16[r], t16[r + 8]);
#pragma unroll
            for (int r = 0; r < 4; ++r) t16[r] = fmaxf(t16[r], t16[r + 4]);
            float pm = fmaxf(fmaxf(t16[0], t16[1]), fmaxf(t16[2], t16[3]));
            pm = fmaxf(pm, __shfl_xor(pm, 32));
            if (!__all(pm - m_run <= 8.f)) {
                const float mnew = fmaxf(m_run, pm);
                const float sc = exp2f(m_run - mnew);
                m_run = mnew;
                l_run *= sc;
#pragma unroll
                for (int r = 0; r < 16; ++r) { oac0[r] *= sc; oac1[r] *= sc; }
            }
            float a16[16];
#pragma unroll
            for (int r = 0; r < 16; ++r) { s0[r] = exp2f(s0[r] - m_run); }
#pragma unroll
            for (int r = 0; r < 16; ++r) { s1[r] = exp2f(s1[r] - m_run); }
#pragma unroll
            for (int r = 0; r < 16; ++r) a16[r] = s0[r] + s1[r];
#pragma unroll
            for (int r = 0; r < 8; ++r) a16[r] += a16[r + 8];
#pragma unroll
            for (int r = 0; r < 4; ++r) a16[r] += a16[r + 4];
            float sum = (a16[0] + a16[1]) + (a16[2] + a16[3]);
            sum += __shfl_xor(sum, 32);
            l_run += sum;

            u32t pk0[8], pk1[8];
#pragma unroll
            for (int w = 0; w < 8; ++w) {
                float a0 = s0[2 * w], b0 = s0[2 * w + 1];
                float a1 = s1[2 * w], b1 = s1[2 * w + 1];
                asm("v_cvt_pk_bf16_f32 %0, %1, %2" : "=v"(pk0[w]) : "v"(a0), "v"(b0));
                asm("v_cvt_pk_bf16_f32 %0, %1, %2" : "=v"(pk1[w]) : "v"(a1), "v"(b1));
            }
            asm("v_permlane32_swap_b32 %0, %1" : "+v"(pk0[0]), "+v"(pk0[2]));
            asm("v_permlane32_swap_b32 %0, %1" : "+v"(pk0[1]), "+v"(pk0[3]));
            asm("v_permlane32_swap_b32 %0, %1" : "+v"(pk0[4]), "+v"(pk0[6]));
            asm("v_permlane32_swap_b32 %0, %1" : "+v"(pk0[5]), "+v"(pk0[7]));
            asm("v_permlane32_swap_b32 %0, %1" : "+v"(pk1[0]), "+v"(pk1[2]));
            asm("v_permlane32_swap_b32 %0, %1" : "+v"(pk1[1]), "+v"(pk1[3]));
            asm("v_permlane32_swap_b32 %0, %1" : "+v"(pk1[4]), "+v"(pk1[6]));
            asm("v_permlane32_swap_b32 %0, %1" : "+v"(pk1[5]), "+v"(pk1[7]));
            bf16x8 pf[4];
            {
                uint4 t0 = {pk0[0], pk0[1], pk0[2], pk0[3]};
                uint4 t1 = {pk0[4], pk0[5], pk0[6], pk0[7]};
                uint4 t2 = {pk1[0], pk1[1], pk1[2], pk1[3]};
                uint4 t3 = {pk1[4], pk1[5], pk1[6], pk1[7]};
                pf[0] = __builtin_bit_cast(bf16x8, t0);
                pf[1] = __builtin_bit_cast(bf16x8, t1);
                pf[2] = __builtin_bit_cast(bf16x8, t2);
                pf[3] = __builtin_bit_cast(bf16x8, t3);
            }

            const u16* vbase = smem + 16640 + cur * 8704;
#pragma unroll
            for (int km = 0; km < 4; ++km) {
                bf16x8 vf = ld_frag(vbase + l31 * 136 +
                                    ((s * 8 + ((km * 2 + lh) ^ vsw)) * 8));
                oac0 = __builtin_amdgcn_mfma_f32_32x32x16_bf16(vf, pf[km], oac0, 0, 0, 0);
            }
#pragma unroll
            for (int km = 0; km < 4; ++km) {
                bf16x8 vf = ld_frag(vbase + (32 + l31) * 136 +
                                    ((s * 8 + ((km * 2 + lh) ^ vsw)) * 8));
                oac1 = __builtin_amdgcn_mfma_f32_32x32x16_bf16(vf, pf[km], oac1, 0, 0, 0);
            }
        }

        if (pre) writeV(cur ^ 1);
        __syncthreads();
    }

    const float inv = 1.f / l_run;
    u16* osh = smem + wid * 2240;
#pragma unroll
    for (int r = 0; r < 16; ++r) {
        int dl = (r & 3) + 8 * (r >> 2) + 4 * lh;
        osh[l31 * 70 + dl] = f2bfu(oac0[r] * inv);
        osh[l31 * 70 + 32 + dl] = f2bfu(oac1[r] * inv);
    }
    __syncthreads();
    {
        const u16* rs = osh + l31 * 70 + lh * 32;
        u16* op = o + (size_t)(b * SEQ_T + qrow0 + l31) * DM + h * HD + lh * 32;
        u32t w[16];
#pragma unroll
        for (int i = 0; i < 16; ++i) w[i] = *reinterpret_cast<const u32t*>(rs + i * 2);
#pragma unroll
        for (int i = 0; i < 4; ++i) {
            uint4 t = {w[4 * i], w[4 * i + 1], w[4 * i + 2], w[4 * i + 3]};
            *reinterpret_cast<uint4*>(op + 8 * i) = t;
        }
    }
}

extern "C" void kernel_launch(void* const* d_in, const int* in_sizes, int n_in,
                              void* d_out, int out_size, void* d_ws, size_t ws_size,
                              hipStream_t stream) {
    const float* x = (const float*)d_in[0];
    const float* Wqkv = (const float*)d_in[1];
    const float* bqkv = (const float*)d_in[2];
    const float* Wproj = (const float*)d_in[3];
    const float* bproj = (const float*)d_in[4];
    float* out = (float*)d_out;
    char* ws = (char*)d_ws;

    u16* xb   = (u16*)(ws);                         // 16,777,216 B
    u16* wtq  = (u16*)(ws + 16777216);              //  6,291,456 B
    u16* wtp  = (u16*)(ws + 23068672);              //  2,097,152 B
    u16* qkvb = (u16*)(ws + 25165824);              // 50,331,648 B
    u16* ob   = (u16*)(ws + 75497472);              // 16,777,216 B

    cvt_x_kernel<<<4096, 256, 0, stream>>>(x, xb);
    trans_w<<<dim3(3072 / 64, 1024 / 64), 256, 0, stream>>>(Wqkv, wtq, 1024, 3072);
    trans_w<<<dim3(1024 / 64, 1024 / 64), 256, 0, stream>>>(Wproj, wtp, 1024, 1024);

    // gemm1: 8192x3072x1024, 256x128 tiles -> 32*24 = 768 blocks
    gemm_p3<0, 1><<<768, 512, 0, stream>>>(
        xb, wtq, bqkv, nullptr, qkvb, 8192, 3072, 1024);

    attn_kernel<<<512, 512, 0, stream>>>(qkvb, ob);

    // gemm2: 8192x1024x1024 -> 32*8 = 256 blocks
    gemm_p3<1, 0><<<256, 512, 0, stream>>>(
        ob, wtp, bproj, out, nullptr, 8192, 1024, 1024);
}

// Round 18
// 203.749 us; speedup vs baseline: 2.0607x; 1.0180x over previous
//
#include <hip/hip_runtime.h>
#include <hip/hip_bf16.h>
#include <stdint.h>

using u16 = unsigned short;
using u32t = unsigned int;
typedef __bf16 bf16x8 __attribute__((ext_vector_type(8)));
typedef float f32x4 __attribute__((ext_vector_type(4)));
typedef float f32x16 __attribute__((ext_vector_type(16)));

#define SEQ_T 2048
#define DM 1024
#define NH 16
#define HD 64
#define NB 4

__device__ inline u16 f2bfu(float f) {
    __hip_bfloat16 h = __float2bfloat16(f);
    return __builtin_bit_cast(u16, h);
}

__device__ inline bf16x8 ld_frag(const u16* p) {
    return __builtin_bit_cast(bf16x8, *reinterpret_cast<const uint4*>(p));
}

__device__ inline void gload_lds16(const u16* g, u16* l) {
    __builtin_amdgcn_global_load_lds(
        (const __attribute__((address_space(1))) void*)g,
        (__attribute__((address_space(3))) void*)l, 16, 0, 0);
}

// ---------------- convert x (f32 -> bf16), 8 elems/thread ----------------
__global__ __launch_bounds__(256) void cvt_x_kernel(const float* __restrict__ x,
                                                    u16* __restrict__ o) {
    size_t i = (size_t)blockIdx.x * 256 + threadIdx.x;
    const float4* xv = reinterpret_cast<const float4*>(x);
    float4 a = xv[2 * i];
    float4 b = xv[2 * i + 1];
    u16 r[8] = {f2bfu(a.x), f2bfu(a.y), f2bfu(a.z), f2bfu(a.w),
                f2bfu(b.x), f2bfu(b.y), f2bfu(b.z), f2bfu(b.w)};
    *reinterpret_cast<uint4*>(o + i * 8) = *reinterpret_cast<const uint4*>(r);
}

// ---------------- transpose + convert W[K][N] f32 -> Wt[N][K] bf16 ----------------
__global__ __launch_bounds__(256) void trans_w(const float* __restrict__ W,
                                               u16* __restrict__ Wt,
                                               int K, int N) {
    __shared__ __align__(16) float tile[64][72];
    int k0 = blockIdx.y * 64, n0 = blockIdx.x * 64;
    int tid = threadIdx.x;
#pragma unroll
    for (int p = 0; p < 4; ++p) {
        int idx = p * 256 + tid;
        int r = idx >> 4, c = (idx & 15) * 4;
        float4 v = *reinterpret_cast<const float4*>(&W[(size_t)(k0 + r) * N + n0 + c]);
        *reinterpret_cast<float4*>(&tile[r][c]) = v;
    }
    __syncthreads();
#pragma unroll
    for (int p = 0; p < 4; ++p) {
        int idx = p * 256 + tid;
        int nr = idx >> 4, kg = (idx & 15) * 4;
        u16 u[4];
#pragma unroll
        for (int j = 0; j < 4; ++j) u[j] = f2bfu(tile[kg + j][nr]);
        *reinterpret_cast<uint2*>(&Wt[(size_t)(n0 + nr) * K + k0 + kg]) =
            *reinterpret_cast<const uint2*>(u);
    }
}

// ---------------- deep-pipelined GEMM (unchanged from round 17) ----------------
template <int F32OUT, int SCALEQ>
__global__ __launch_bounds__(512, 2) void gemm_p3(const u16* __restrict__ A,
                                                  const u16* __restrict__ Bt,
                                                  const float* __restrict__ bias,
                                                  float* __restrict__ Cf,
                                                  u16* __restrict__ Cb,
                                                  int M, int N, int K) {
    __shared__ __align__(16) u16 smem[73728];
    const int tid = threadIdx.x;
    const int wid = tid >> 6, lane = tid & 63;
    const int llo = lane & 15, lhi = lane >> 4;
    const int wm = wid >> 1, wn = wid & 1;
    const int cpx = gridDim.x >> 3;
    const int swz = (blockIdx.x & 7) * cpx + (blockIdx.x >> 3);
    const int nb = N >> 7;
    const int m0 = (swz / nb) << 8, n0 = (swz % nb) << 7;
    const int T = K >> 6;

    f32x4 acc[4][4];
#pragma unroll
    for (int i = 0; i < 4; ++i)
#pragma unroll
        for (int j = 0; j < 4; ++j) acc[i][j] = (f32x4){0.f, 0.f, 0.f, 0.f};

    auto stage2 = [&](int t2, int p, int sb) {
        const int kbase = t2 << 6;
#pragma unroll
        for (int j = 0; j < 2; ++j) {
            int c = (j * 8 + wid) * 64 + lane;
            int row = c >> 3, cc = c & 7;
            int kc = cc ^ (row & 7);
            const u16* src = A + (size_t)(m0 + p * 128 + row) * K + kbase + kc * 8;
            gload_lds16(src, smem + sb + p * 8192 + (j * 8 + wid) * 512);
        }
        {
            int c = wid * 64 + lane;
            int row = c >> 3, cc = c & 7;
            int kc = cc ^ (row & 7);
            const u16* src = Bt + (size_t)(n0 + p * 64 + row) * K + kbase + kc * 8;
            gload_lds16(src, smem + sb + 16384 + p * 4096 + wid * 512);
        }
    };

    stage2(0, 0, 0);
    stage2(0, 1, 0);
    stage2(1, 0, 24576);
    stage2(1, 1, 24576);

    const int l7 = llo & 7;
    for (int t = 0; t < T; ++t) {
        const int cb = (t % 3) * 24576;
        const u16* Ab = smem + cb;
        const u16* Bb = smem + cb + 16384;
        const int sb = ((t + 2) % 3) * 24576;
        const bool pre = (t + 2 < T);
        bf16x8 bfr[4][2];
#pragma unroll
        for (int p = 0; p < 2; ++p) {
            if (p == 0) {
                if (t == T - 1)
                    asm volatile("s_waitcnt vmcnt(0)" ::: "memory");
                else
                    asm volatile("s_waitcnt vmcnt(6)" ::: "memory");
                __builtin_amdgcn_sched_barrier(0);
            }
            __builtin_amdgcn_s_barrier();
            __builtin_amdgcn_sched_barrier(0);
            if (p == 0) {
#pragma unroll
                for (int nf = 0; nf < 4; ++nf) {
                    int lc = wn * 64 + nf * 16 + llo;
#pragma unroll
                    for (int ks = 0; ks < 2; ++ks)
                        bfr[nf][ks] =
                            ld_frag(Bb + lc * 64 + (((ks * 4 + lhi) ^ l7) * 8));
                }
            }
            bf16x8 af[2][2];
#pragma unroll
            for (int j = 0; j < 2; ++j) {
                int row = wm * 64 + (p * 2 + j) * 16 + llo;
#pragma unroll
                for (int ks = 0; ks < 2; ++ks)
                    af[j][ks] = ld_frag(Ab + row * 64 + (((ks * 4 + lhi) ^ l7) * 8));
            }
            if (pre) stage2(t + 2, p, sb);
            __builtin_amdgcn_s_setprio(1);
#pragma unroll
            for (int j = 0; j < 2; ++j)
#pragma unroll
                for (int nf = 0; nf < 4; ++nf)
#pragma unroll
                    for (int ks = 0; ks < 2; ++ks)
                        acc[p * 2 + j][nf] = __builtin_amdgcn_mfma_f32_16x16x32_bf16(
                            af[j][ks], bfr[nf][ks], acc[p * 2 + j][nf], 0, 0, 0);
            __builtin_amdgcn_s_setprio(0);
        }
    }

    const float SC2 = 0.18033688f;
    const int row_base = m0 + wm * 64;
    const int col_base = n0 + wn * 64;
#pragma unroll
    for (int nf = 0; nf < 4; ++nf) {
        int col = col_base + nf * 16 + llo;
        float bv = bias[col];
        const bool doScale = SCALEQ && (col < 1024);
#pragma unroll
        for (int mf = 0; mf < 4; ++mf) {
#pragma unroll
            for (int r = 0; r < 4; ++r) {
                int row = row_base + mf * 16 + lhi * 4 + r;
                float v = acc[mf][nf][r] + bv;
                if (doScale) v *= SC2;
                if (F32OUT)
                    Cf[(size_t)row * N + col] = v;
                else
                    Cb[(size_t)row * N + col] = f2bfu(v);
            }
        }
    }
}

// ---------------- causal flash attention, counted-vmcnt barriers (T4) ----------------
// K ring-2 staged as two 64-row halves; tile-end barrier = lgkmcnt(0)+vmcnt(1)+s_barrier
// (next tile's K-half-0 landed, half-1 in flight); mid-tile vmcnt(4) guards half-1.
// No vmcnt(0) drain in the main loop.
__global__ __launch_bounds__(512, 2) void attn_kernel(const u16* __restrict__ qkv,
                                                      u16* __restrict__ o) {
    __shared__ __align__(16) u16 smem[34048];  // K:2x8320 @0, Vt:2x8704 @16640
    const int bid = blockIdx.x;
    const int hmap[8] = {7, 6, 5, 4, 0, 1, 2, 3};  // h(g+4)=h(g)^7
    const int bh = bid & 63;
    const int qc = hmap[bid >> 6] ^ ((bh & 1) * 7);  // robust pair-sum=7 both mappings
    const int b = bh >> 4, h = bh & 15;
    const int tid = threadIdx.x;
    const int wid = tid >> 6, lane = tid & 63;
    const int l31 = lane & 31, lh = lane >> 5;
    const u16* base = qkv + (size_t)b * SEQ_T * (3 * DM);
    const int qrow0 = qc * 256 + wid * 32;
    const int q_abs = qrow0 + l31;
    const int nkv2 = 2 * qc + 2;

    bf16x8 qf[4];
    {
        const u16* qp = base + (size_t)q_abs * (3 * DM) + h * HD + lh * 8;
#pragma unroll
        for (int km = 0; km < 4; ++km) qf[km] = ld_frag(qp + km * 16);
    }

    f32x16 oac0, oac1;
#pragma unroll
    for (int r = 0; r < 16; ++r) { oac0[r] = 0.f; oac1[r] = 0.f; }
    float m_run = -1e30f, l_run = 0.f;

    uint4 va, vb;
    const int vpr = tid >> 3, vm = tid & 7;

    auto stageK = [&](int kb2, int bi2) {  // p0 = rows 0-63 (sub-step 0), p1 = 64-127
#pragma unroll
        for (int p = 0; p < 2; ++p) {
            int kv = p * 64 + wid * 8 + (lane >> 3);
            int cl = lane & 7;
            const u16* src = base + (size_t)(kb2 * 128 + kv) * (3 * DM) + DM + h * HD +
                             ((cl ^ (kv & 7)) * 8);
            gload_lds16(src, smem + bi2 * 8320 + (p * 8 + wid) * 520);
        }
    };
    auto loadV = [&](int kb2) {
        const u16* vp =
            base + (size_t)(kb2 * 128 + 2 * vpr) * (3 * DM) + 2 * DM + h * HD + vm * 8;
        va = *reinterpret_cast<const uint4*>(vp);
        vb = *reinterpret_cast<const uint4*>(vp + 3 * DM);
    };
    auto writeV = [&](int bi2) {
        u16 ua[8], ub[8];
        *reinterpret_cast<uint4*>(ua) = va;
        *reinterpret_cast<uint4*>(ub) = vb;
        const int cbk = vpr >> 2, off = 2 * (vpr & 3);
        const int sw = (2 * vm) & 7;
        u16* vt = smem + 16640 + bi2 * 8704;
#pragma unroll
        for (int j = 0; j < 8; ++j) {
            int d = vm * 8 + j;
            u32t val = (u32t)ua[j] | ((u32t)ub[j] << 16);
            *reinterpret_cast<u32t*>(vt + d * 136 + ((cbk ^ sw) * 8) + off) = val;
        }
    };

    loadV(0);
    stageK(0, 0);
    writeV(0);  // compiler waits loadV's loads; stage p0/p1 remain outstanding
    asm volatile("s_waitcnt lgkmcnt(0)" ::: "memory");
    asm volatile("s_waitcnt vmcnt(1)" ::: "memory");  // K half-0 ready, half-1 flying
    __builtin_amdgcn_sched_barrier(0);
    __builtin_amdgcn_s_barrier();
    __builtin_amdgcn_sched_barrier(0);

    const int vsw = (2 * (l31 >> 3)) & 7;
    const int qmax = qrow0 + 31;
    const int krow0 = (l31 >> 3) * 520 + (l31 & 7) * 64;
    const int krow1 = (4 + (l31 >> 3)) * 520 + (l31 & 7) * 64;

    for (int kb2 = 0; kb2 < nkv2; ++kb2) {
        const int cur = kb2 & 1;
        const bool pre = (kb2 + 1 < nkv2);
        if (pre) { loadV(kb2 + 1); stageK(kb2 + 1, cur ^ 1); }

#pragma unroll
        for (int s = 0; s < 2; ++s) {
            if (s == 1) {
                // wait this tile's K half-1; allow the 4 newer loads (loadV 2 + stage 2)
                if (pre) asm volatile("s_waitcnt vmcnt(4)" ::: "memory");
                else     asm volatile("s_waitcnt vmcnt(0)" ::: "memory");
                __builtin_amdgcn_sched_barrier(0);
            }
            const int kv0 = kb2 * 128 + s * 64;
            if (kv0 > qmax) continue;
            f32x16 s0, s1;
#pragma unroll
            for (int r = 0; r < 16; ++r) { s0[r] = 0.f; s1[r] = 0.f; }
            const u16* kbase = smem + cur * 8320 + s * 4160;
#pragma unroll
            for (int km = 0; km < 4; ++km) {
                bf16x8 kf = ld_frag(kbase + krow0 + (((km * 2 + lh) ^ (l31 & 7)) * 8));
                s0 = __builtin_amdgcn_mfma_f32_32x32x16_bf16(kf, qf[km], s0, 0, 0, 0);
            }
#pragma unroll
            for (int km = 0; km < 4; ++km) {
                bf16x8 kf = ld_frag(kbase + krow1 + (((km * 2 + lh) ^ (l31 & 7)) * 8));
                s1 = __builtin_amdgcn_mfma_f32_32x32x16_bf16(kf, qf[km], s1, 0, 0, 0);
            }

            if (kv0 + 63 > qrow0) {
#pragma unroll
                for (int r = 0; r < 16; ++r) {
                    int ka = kv0 + (r & 3) + 8 * (r >> 2) + 4 * lh;
                    if (ka > q_abs) s0[r] = -1e30f;
                    if (ka + 32 > q_abs) s1[r] = -1e30f;
                }
            }

            float t16[16];
#pragma unroll
            for (int r = 0; r < 16; ++r) t16[r] = fmaxf(s0[r], s1[r]);
#pragma unroll
            for (int r = 0; r < 8; ++r) t16[r] = fmaxf(t16[r], t16[r + 8]);
#pragma unroll
            for (int r = 0; r < 4; ++r) t16[r] = fmaxf(t16[r], t16[r + 4]);
            float pm = fmaxf(fmaxf(t16[0], t16[1]), fmaxf(t16[2], t16[3]));
            pm = fmaxf(pm, __shfl_xor(pm, 32));
            if (!__all(pm - m_run <= 8.f)) {
                const float mnew = fmaxf(m_run, pm);
                const float sc = exp2f(m_run - mnew);
                m_run = mnew;
                l_run *= sc;
#pragma unroll
                for (int r = 0; r < 16; ++r) { oac0[r] *= sc; oac1[r] *= sc; }
            }
            float a16[16];
#pragma unroll
            for (int r = 0; r < 16; ++r) { s0[r] = exp2f(s0[r] - m_run); }
#pragma unroll
            for (int r = 0; r < 16; ++r) { s1[r] = exp2f(s1[r] - m_run); }
#pragma unroll
            for (int r = 0; r < 16; ++r) a16[r] = s0[r] + s1[r];
#pragma unroll
            for (int r = 0; r < 8; ++r) a16[r] += a16[r + 8];
#pragma unroll
            for (int r = 0; r < 4; ++r) a16[r] += a16[r + 4];
            float sum = (a16[0] + a16[1]) + (a16[2] + a16[3]);
            sum += __shfl_xor(sum, 32);
            l_run += sum;

            u32t pk0[8], pk1[8];
#pragma unroll
            for (int w = 0; w < 8; ++w) {
                float a0 = s0[2 * w], b0 = s0[2 * w + 1];
                float a1 = s1[2 * w], b1 = s1[2 * w + 1];
                asm("v_cvt_pk_bf16_f32 %0, %1, %2" : "=v"(pk0[w]) : "v"(a0), "v"(b0));
                asm("v_cvt_pk_bf16_f32 %0, %1, %2" : "=v"(pk1[w]) : "v"(a1), "v"(b1));
            }
            asm("v_permlane32_swap_b32 %0, %1" : "+v"(pk0[0]), "+v"(pk0[2]));
            asm("v_permlane32_swap_b32 %0, %1" : "+v"(pk0[1]), "+v"(pk0[3]));
            asm("v_permlane32_swap_b32 %0, %1" : "+v"(pk0[4]), "+v"(pk0[6]));
            asm("v_permlane32_swap_b32 %0, %1" : "+v"(pk0[5]), "+v"(pk0[7]));
            asm("v_permlane32_swap_b32 %0, %1" : "+v"(pk1[0]), "+v"(pk1[2]));
            asm("v_permlane32_swap_b32 %0, %1" : "+v"(pk1[1]), "+v"(pk1[3]));
            asm("v_permlane32_swap_b32 %0, %1" : "+v"(pk1[4]), "+v"(pk1[6]));
            asm("v_permlane32_swap_b32 %0, %1" : "+v"(pk1[5]), "+v"(pk1[7]));
            bf16x8 pf[4];
            {
                uint4 t0 = {pk0[0], pk0[1], pk0[2], pk0[3]};
                uint4 t1 = {pk0[4], pk0[5], pk0[6], pk0[7]};
                uint4 t2 = {pk1[0], pk1[1], pk1[2], pk1[3]};
                uint4 t3 = {pk1[4], pk1[5], pk1[6], pk1[7]};
                pf[0] = __builtin_bit_cast(bf16x8, t0);
                pf[1] = __builtin_bit_cast(bf16x8, t1);
                pf[2] = __builtin_bit_cast(bf16x8, t2);
                pf[3] = __builtin_bit_cast(bf16x8, t3);
            }

            const u16* vbase = smem + 16640 + cur * 8704;
#pragma unroll
            for (int km = 0; km < 4; ++km) {
                bf16x8 vf = ld_frag(vbase + l31 * 136 +
                                    ((s * 8 + ((km * 2 + lh) ^ vsw)) * 8));
                oac0 = __builtin_amdgcn_mfma_f32_32x32x16_bf16(vf, pf[km], oac0, 0, 0, 0);
            }
#pragma unroll
            for (int km = 0; km < 4; ++km) {
                bf16x8 vf = ld_frag(vbase + (32 + l31) * 136 +
                                    ((s * 8 + ((km * 2 + lh) ^ vsw)) * 8));
                oac1 = __builtin_amdgcn_mfma_f32_32x32x16_bf16(vf, pf[km], oac1, 0, 0, 0);
            }
        }

        if (pre) {
            writeV(cur ^ 1);  // compiler waits loadV; stage(kb2+1) p0/p1 remain
            asm volatile("s_waitcnt lgkmcnt(0)" ::: "memory");
            asm volatile("s_waitcnt vmcnt(1)" ::: "memory");  // next K half-0 landed
        } else {
            asm volatile("s_waitcnt lgkmcnt(0)" ::: "memory");
        }
        __builtin_amdgcn_sched_barrier(0);
        __builtin_amdgcn_s_barrier();
        __builtin_amdgcn_sched_barrier(0);
    }

    const float inv = 1.f / l_run;
    u16* osh = smem + wid * 2240;
#pragma unroll
    for (int r = 0; r < 16; ++r) {
        int dl = (r & 3) + 8 * (r >> 2) + 4 * lh;
        osh[l31 * 70 + dl] = f2bfu(oac0[r] * inv);
        osh[l31 * 70 + 32 + dl] = f2bfu(oac1[r] * inv);
    }
    __syncthreads();
    {
        const u16* rs = osh + l31 * 70 + lh * 32;
        u16* op = o + (size_t)(b * SEQ_T + qrow0 + l31) * DM + h * HD + lh * 32;
        u32t w[16];
#pragma unroll
        for (int i = 0; i < 16; ++i) w[i] = *reinterpret_cast<const u32t*>(rs + i * 2);
#pragma unroll
        for (int i = 0; i < 4; ++i) {
            uint4 t = {w[4 * i], w[4 * i + 1], w[4 * i + 2], w[4 * i + 3]};
            *reinterpret_cast<uint4*>(op + 8 * i) = t;
        }
    }
}

extern "C" void kernel_launch(void* const* d_in, const int* in_sizes, int n_in,
                              void* d_out, int out_size, void* d_ws, size_t ws_size,
                              hipStream_t stream) {
    const float* x = (const float*)d_in[0];
    const float* Wqkv = (const float*)d_in[1];
    const float* bqkv = (const float*)d_in[2];
    const float* Wproj = (const float*)d_in[3];
    const float* bproj = (const float*)d_in[4];
    float* out = (float*)d_out;
    char* ws = (char*)d_ws;

    u16* xb   = (u16*)(ws);                         // 16,777,216 B
    u16* wtq  = (u16*)(ws + 16777216);              //  6,291,456 B
    u16* wtp  = (u16*)(ws + 23068672);              //  2,097,152 B
    u16* qkvb = (u16*)(ws + 25165824);              // 50,331,648 B
    u16* ob   = (u16*)(ws + 75497472);              // 16,777,216 B

    cvt_x_kernel<<<4096, 256, 0, stream>>>(x, xb);
    trans_w<<<dim3(3072 / 64, 1024 / 64), 256, 0, stream>>>(Wqkv, wtq, 1024, 3072);
    trans_w<<<dim3(1024 / 64, 1024 / 64), 256, 0, stream>>>(Wproj, wtp, 1024, 1024);

    gemm_p3<0, 1><<<768, 512, 0, stream>>>(
        xb, wtq, bqkv, nullptr, qkvb, 8192, 3072, 1024);

    attn_kernel<<<512, 512, 0, stream>>>(qkvb, ob);

    gemm_p3<1, 0><<<256, 512, 0, stream>>>(
        ob, wtp, bproj, out, nullptr, 8192, 1024, 1024);
}